// Round 1
// baseline (667.512 us; speedup 1.0000x reference)
//
#include <hip/hip_runtime.h>

#define DI __device__ __forceinline__

constexpr int B_ = 16;
constexpr int C_ = 512;
constexpr int W_ = 2048;
constexpr int C4 = C_ / 4;   // 128
constexpr int C2 = C_ / 2;   // 256
constexpr int Q_ = W_ / 2;   // 1024

DI float bf16_to_f(unsigned short u) {
  union { unsigned int i; float f; } c; c.i = ((unsigned int)u) << 16; return c.f;
}
DI unsigned short f_to_bf16(float v) {
  union { float f; unsigned int i; } c; c.f = v;
  unsigned int x = c.i;
  return (unsigned short)((x + 0x7FFFu + ((x >> 16) & 1u)) >> 16);
}

// ---------------------------------------------------------------------------
// K1: fgh = [wf;wg;wh] @ x[b]  (512x512 @ 512x2048), bias + maxpool2 fused.
// 128x128 tile, 256 thr, 8x8 microtile. grid (W/128, 4, B)
// ---------------------------------------------------------------------------
__global__ __launch_bounds__(256)
void k_fgh(const float* __restrict__ x,
           const float* __restrict__ wf, const float* __restrict__ bfp,
           const float* __restrict__ wg, const float* __restrict__ bgp,
           const float* __restrict__ wh, const float* __restrict__ bhp,
           float* __restrict__ f, float* __restrict__ g, float* __restrict__ h)
{
  const int b  = blockIdx.z;
  const int rt = blockIdx.y;            // 0:f  1:g  2,3:h
  const int w0 = blockIdx.x * 128;

  const float* Wm; const float* bias; int rloc0;
  if (rt == 0)      { Wm = wf; bias = bfp; rloc0 = 0; }
  else if (rt == 1) { Wm = wg; bias = bgp; rloc0 = 0; }
  else              { Wm = wh; bias = bhp; rloc0 = (rt - 2) * 128; }

  __shared__ float a_lds[8][132];
  __shared__ float b_lds[8][132];

  const int t  = threadIdx.x;
  const int tx = t & 15, ty = t >> 4;

  float acc[8][8] = {};

  for (int c0 = 0; c0 < C_; c0 += 8) {
    {
      const int idx = t * 4;
      const int r  = idx >> 3;
      const int cc = idx & 7;
      const float4 v = *(const float4*)&Wm[(size_t)(rloc0 + r) * C_ + c0 + cc];
      a_lds[cc + 0][r] = v.x; a_lds[cc + 1][r] = v.y;
      a_lds[cc + 2][r] = v.z; a_lds[cc + 3][r] = v.w;
    }
    {
      const int idx = t * 4;
      const int cc = idx >> 7;
      const int ww = idx & 127;
      const float4 v = *(const float4*)&x[((size_t)b * C_ + c0 + cc) * W_ + w0 + ww];
      *(float4*)&b_lds[cc][ww] = v;
    }
    __syncthreads();
    #pragma unroll
    for (int kk = 0; kk < 8; ++kk) {
      float av[8], bv[8];
      *(float4*)&av[0] = *(const float4*)&a_lds[kk][ty * 8];
      *(float4*)&av[4] = *(const float4*)&a_lds[kk][ty * 8 + 4];
      *(float4*)&bv[0] = *(const float4*)&b_lds[kk][tx * 8];
      *(float4*)&bv[4] = *(const float4*)&b_lds[kk][tx * 8 + 4];
      #pragma unroll
      for (int i = 0; i < 8; ++i)
        #pragma unroll
        for (int j = 0; j < 8; ++j)
          acc[i][j] += av[i] * bv[j];
    }
    __syncthreads();
  }

  if (rt == 1) {
    #pragma unroll
    for (int i = 0; i < 8; ++i) {
      const int ch = ty * 8 + i;
      const float bb = bias[ch];
      float4 v0, v1;
      v0.x = acc[i][0] + bb; v0.y = acc[i][1] + bb;
      v0.z = acc[i][2] + bb; v0.w = acc[i][3] + bb;
      v1.x = acc[i][4] + bb; v1.y = acc[i][5] + bb;
      v1.z = acc[i][6] + bb; v1.w = acc[i][7] + bb;
      float* dst = &g[((size_t)b * C4 + ch) * W_ + w0 + tx * 8];
      *(float4*)&dst[0] = v0;
      *(float4*)&dst[4] = v1;
    }
  } else {
    float* dstbase = (rt == 0) ? f : h;
    const int nch  = (rt == 0) ? C4 : C2;
    #pragma unroll
    for (int i = 0; i < 8; ++i) {
      const int ch = rloc0 + ty * 8 + i;
      const float bb = bias[ch];
      float4 v;
      v.x = fmaxf(acc[i][0], acc[i][1]) + bb;
      v.y = fmaxf(acc[i][2], acc[i][3]) + bb;
      v.z = fmaxf(acc[i][4], acc[i][5]) + bb;
      v.w = fmaxf(acc[i][6], acc[i][7]) + bb;
      *(float4*)&dstbase[((size_t)b * nch + ch) * Q_ + (w0 >> 1) + tx * 4] = v;
    }
  }
}

// ---------------------------------------------------------------------------
// K2: s[q,k] = sum_c f[c,q] g[c,k], softmax over k (full 2048 row in block),
// write beta as bf16. Block: 8 q rows x 2048 k, 256 thr (8 k each).
// grid (Q/8, B)
// ---------------------------------------------------------------------------
__global__ __launch_bounds__(256)
void k_attn(const float* __restrict__ f, const float* __restrict__ g,
            unsigned short* __restrict__ beta)
{
  const int b    = blockIdx.y;
  const int q0   = blockIdx.x * 8;
  const int t    = threadIdx.x;
  const int k0   = t * 8;
  const int lane = t & 63, wv = t >> 6;

  __shared__ float f_lds[128][8];
  __shared__ float redm[4][8];
  __shared__ float redl[4][8];

  {
    const int idx = t * 4;
    const int c = idx >> 3;
    const int j = idx & 7;
    *(float4*)&f_lds[c][j] = *(const float4*)&f[((size_t)b * C4 + c) * Q_ + q0 + j];
  }
  __syncthreads();

  float acc[8][8] = {};   // [q][k]
  const float* gp = g + (size_t)b * C4 * W_ + k0;
  for (int c = 0; c < C4; ++c) {
    float fv[8], gv[8];
    *(float4*)&fv[0] = *(const float4*)&f_lds[c][0];
    *(float4*)&fv[4] = *(const float4*)&f_lds[c][4];
    *(float4*)&gv[0] = *(const float4*)&gp[(size_t)c * W_];
    *(float4*)&gv[4] = *(const float4*)&gp[(size_t)c * W_ + 4];
    #pragma unroll
    for (int j = 0; j < 8; ++j)
      #pragma unroll
      for (int i = 0; i < 8; ++i)
        acc[j][i] += fv[j] * gv[i];
  }

  // row max over k
  float m[8];
  #pragma unroll
  for (int j = 0; j < 8; ++j) {
    float v = acc[j][0];
    #pragma unroll
    for (int i = 1; i < 8; ++i) v = fmaxf(v, acc[j][i]);
    #pragma unroll
    for (int off = 32; off > 0; off >>= 1) v = fmaxf(v, __shfl_xor(v, off));
    m[j] = v;
  }
  if (lane == 0) {
    #pragma unroll
    for (int j = 0; j < 8; ++j) redm[wv][j] = m[j];
  }
  __syncthreads();
  #pragma unroll
  for (int j = 0; j < 8; ++j)
    m[j] = fmaxf(fmaxf(redm[0][j], redm[1][j]), fmaxf(redm[2][j], redm[3][j]));

  // exp + row sum
  float l[8];
  #pragma unroll
  for (int j = 0; j < 8; ++j) {
    float s = 0.f;
    #pragma unroll
    for (int i = 0; i < 8; ++i) { acc[j][i] = __expf(acc[j][i] - m[j]); s += acc[j][i]; }
    #pragma unroll
    for (int off = 32; off > 0; off >>= 1) s += __shfl_xor(s, off);
    l[j] = s;
  }
  if (lane == 0) {
    #pragma unroll
    for (int j = 0; j < 8; ++j) redl[wv][j] = l[j];
  }
  __syncthreads();

  #pragma unroll
  for (int j = 0; j < 8; ++j) {
    const float inv = 1.f / (redl[0][j] + redl[1][j] + redl[2][j] + redl[3][j]);
    unsigned short o8[8];
    #pragma unroll
    for (int i = 0; i < 8; ++i) o8[i] = f_to_bf16(acc[j][i] * inv);
    *(uint4*)&beta[((size_t)b * Q_ + q0 + j) * W_ + k0] = *(uint4*)o8;
  }
}

// ---------------------------------------------------------------------------
// K3: o1[c,k] = sum_q h[c,q] beta[q,k].  [256x1024]@[1024x2048] per batch.
// 128x128 tile. grid (W/128, C2/128, B)
// ---------------------------------------------------------------------------
__global__ __launch_bounds__(256)
void k_o1(const float* __restrict__ h, const unsigned short* __restrict__ beta,
          float* __restrict__ o1)
{
  const int b  = blockIdx.z;
  const int c0 = blockIdx.y * 128;
  const int w0 = blockIdx.x * 128;

  __shared__ float a_lds[8][132];
  __shared__ float b_lds[8][132];

  const int t = threadIdx.x, tx = t & 15, ty = t >> 4;
  float acc[8][8] = {};

  for (int q0 = 0; q0 < Q_; q0 += 8) {
    {
      const int idx = t * 4, r = idx >> 3, cc = idx & 7;
      const float4 v = *(const float4*)&h[((size_t)b * C2 + c0 + r) * Q_ + q0 + cc];
      a_lds[cc + 0][r] = v.x; a_lds[cc + 1][r] = v.y;
      a_lds[cc + 2][r] = v.z; a_lds[cc + 3][r] = v.w;
    }
    {
      const int idx = t * 4, cc = idx >> 7, ww = idx & 127;
      const ushort4 v = *(const ushort4*)&beta[((size_t)b * Q_ + q0 + cc) * W_ + w0 + ww];
      float4 o;
      o.x = bf16_to_f(v.x); o.y = bf16_to_f(v.y);
      o.z = bf16_to_f(v.z); o.w = bf16_to_f(v.w);
      *(float4*)&b_lds[cc][ww] = o;
    }
    __syncthreads();
    #pragma unroll
    for (int kk = 0; kk < 8; ++kk) {
      float av[8], bv[8];
      *(float4*)&av[0] = *(const float4*)&a_lds[kk][ty * 8];
      *(float4*)&av[4] = *(const float4*)&a_lds[kk][ty * 8 + 4];
      *(float4*)&bv[0] = *(const float4*)&b_lds[kk][tx * 8];
      *(float4*)&bv[4] = *(const float4*)&b_lds[kk][tx * 8 + 4];
      #pragma unroll
      for (int i = 0; i < 8; ++i)
        #pragma unroll
        for (int j = 0; j < 8; ++j)
          acc[i][j] += av[i] * bv[j];
    }
    __syncthreads();
  }

  #pragma unroll
  for (int i = 0; i < 8; ++i) {
    float* dst = &o1[((size_t)b * C2 + c0 + ty * 8 + i) * W_ + w0 + tx * 8];
    float4 v0, v1;
    v0.x = acc[i][0]; v0.y = acc[i][1]; v0.z = acc[i][2]; v0.w = acc[i][3];
    v1.x = acc[i][4]; v1.y = acc[i][5]; v1.z = acc[i][6]; v1.w = acc[i][7];
    *(float4*)&dst[0] = v0;
    *(float4*)&dst[4] = v1;
  }
}

// ---------------------------------------------------------------------------
// K4: out = gamma * (wa @ o1 + ba) + x.  [512x256]@[256x2048] per batch.
// grid (W/128, C/128, B)
// ---------------------------------------------------------------------------
__global__ __launch_bounds__(256)
void k_out(const float* __restrict__ wa, const float* __restrict__ ba,
           const float* __restrict__ o1, const float* __restrict__ x,
           const float* __restrict__ gamma, float* __restrict__ out)
{
  const int b  = blockIdx.z;
  const int r0 = blockIdx.y * 128;
  const int w0 = blockIdx.x * 128;

  __shared__ float a_lds[8][132];
  __shared__ float b_lds[8][132];

  const int t = threadIdx.x, tx = t & 15, ty = t >> 4;
  float acc[8][8] = {};

  for (int c0 = 0; c0 < C2; c0 += 8) {
    {
      const int idx = t * 4, r = idx >> 3, cc = idx & 7;
      const float4 v = *(const float4*)&wa[(size_t)(r0 + r) * C2 + c0 + cc];
      a_lds[cc + 0][r] = v.x; a_lds[cc + 1][r] = v.y;
      a_lds[cc + 2][r] = v.z; a_lds[cc + 3][r] = v.w;
    }
    {
      const int idx = t * 4, cc = idx >> 7, ww = idx & 127;
      const float4 v = *(const float4*)&o1[((size_t)b * C2 + c0 + cc) * W_ + w0 + ww];
      *(float4*)&b_lds[cc][ww] = v;
    }
    __syncthreads();
    #pragma unroll
    for (int kk = 0; kk < 8; ++kk) {
      float av[8], bv[8];
      *(float4*)&av[0] = *(const float4*)&a_lds[kk][ty * 8];
      *(float4*)&av[4] = *(const float4*)&a_lds[kk][ty * 8 + 4];
      *(float4*)&bv[0] = *(const float4*)&b_lds[kk][tx * 8];
      *(float4*)&bv[4] = *(const float4*)&b_lds[kk][tx * 8 + 4];
      #pragma unroll
      for (int i = 0; i < 8; ++i)
        #pragma unroll
        for (int j = 0; j < 8; ++j)
          acc[i][j] += av[i] * bv[j];
    }
    __syncthreads();
  }

  const float gm = gamma[0];
  #pragma unroll
  for (int i = 0; i < 8; ++i) {
    const int co = r0 + ty * 8 + i;
    const float bb = ba[co];
    const size_t base = ((size_t)b * C_ + co) * W_ + w0 + tx * 8;
    const float4 xv0 = *(const float4*)&x[base];
    const float4 xv1 = *(const float4*)&x[base + 4];
    float4 v0, v1;
    v0.x = gm * (acc[i][0] + bb) + xv0.x;
    v0.y = gm * (acc[i][1] + bb) + xv0.y;
    v0.z = gm * (acc[i][2] + bb) + xv0.z;
    v0.w = gm * (acc[i][3] + bb) + xv0.w;
    v1.x = gm * (acc[i][4] + bb) + xv1.x;
    v1.y = gm * (acc[i][5] + bb) + xv1.y;
    v1.z = gm * (acc[i][6] + bb) + xv1.z;
    v1.w = gm * (acc[i][7] + bb) + xv1.w;
    *(float4*)&out[base] = v0;
    *(float4*)&out[base + 4] = v1;
  }
}

// ---------------------------------------------------------------------------
extern "C" void kernel_launch(void* const* d_in, const int* in_sizes, int n_in,
                              void* d_out, int out_size, void* d_ws, size_t ws_size,
                              hipStream_t stream)
{
  const float* x     = (const float*)d_in[0];
  const float* wf    = (const float*)d_in[1];
  const float* bfp   = (const float*)d_in[2];
  const float* wg    = (const float*)d_in[3];
  const float* bgp   = (const float*)d_in[4];
  const float* wh    = (const float*)d_in[5];
  const float* bhp   = (const float*)d_in[6];
  const float* wa    = (const float*)d_in[7];
  const float* ba    = (const float*)d_in[8];
  const float* gamma = (const float*)d_in[9];
  float* out = (float*)d_out;

  char* ws = (char*)d_ws;
  size_t off = 0;
  float* f = (float*)(ws + off);              off += (size_t)B_ * C4 * Q_ * 4;   //  8 MB
  float* g = (float*)(ws + off);              off += (size_t)B_ * C4 * W_ * 4;   // 16 MB
  float* h = (float*)(ws + off);              off += (size_t)B_ * C2 * Q_ * 4;   // 16 MB
  unsigned short* beta = (unsigned short*)(ws + off); off += (size_t)B_ * Q_ * W_ * 2; // 64 MB
  float* o1 = (float*)(ws + off);             off += (size_t)B_ * C2 * W_ * 4;   // 32 MB

  dim3 blk(256);
  k_fgh<<<dim3(W_ / 128, 4, B_), blk, 0, stream>>>(x, wf, bfp, wg, bgp, wh, bhp, f, g, h);
  k_attn<<<dim3(Q_ / 8, B_), blk, 0, stream>>>(f, g, beta);
  k_o1<<<dim3(W_ / 128, C2 / 128, B_), blk, 0, stream>>>(h, beta, o1);
  k_out<<<dim3(W_ / 128, C_ / 128, B_), blk, 0, stream>>>(wa, ba, o1, x, gamma, out);
}

// Round 4
// 288.199 us; speedup vs baseline: 2.3162x; 2.3162x over previous
//
#include <hip/hip_runtime.h>

#define DI __device__ __forceinline__

constexpr int B_ = 16;
constexpr int C_ = 512;
constexpr int W_ = 2048;
constexpr int C4 = 128;
constexpr int C2 = 256;
constexpr int Q_ = 1024;

typedef short bf16x8 __attribute__((ext_vector_type(8)));
typedef float f32x4 __attribute__((ext_vector_type(4)));

DI f32x4 MFMA(bf16x8 a, bf16x8 b, f32x4 c) {
  return __builtin_amdgcn_mfma_f32_16x16x32_bf16(a, b, c, 0, 0, 0);
}

DI unsigned short f2bf(float v) {
  union { float f; unsigned int i; } c; c.f = v;
  return (unsigned short)((c.i + 0x7FFFu + ((c.i >> 16) & 1u)) >> 16);
}

// Fragment load from row-major bf16 matrix (leading dim ld, in elements).
// lane l -> row (l&15), k-offset (l>>4)*8  (16B contiguous per lane).
DI bf16x8 ldfrag(const unsigned short* p, int ld) {
  const int l = threadIdx.x & 63;
  return *(const bf16x8*)(p + (size_t)(l & 15) * ld + ((l >> 4) << 3));
}

// ---------------------------------------------------------------------------
// Prep 1: convert weights to bf16.  dst layout: [wf 64K][wg 64K][wh 128K][wa 128K]
// ---------------------------------------------------------------------------
__global__ __launch_bounds__(256)
void k_cvt(const float* __restrict__ wf, const float* __restrict__ wg,
           const float* __restrict__ wh, const float* __restrict__ wa,
           unsigned short* __restrict__ dst)
{
  const int i = blockIdx.x * 256 + threadIdx.x;   // grid covers 393216
  float v;
  if (i < 65536)        v = wf[i];
  else if (i < 131072)  v = wg[i - 65536];
  else if (i < 262144)  v = wh[i - 131072];
  else                  v = wa[i - 262144];
  dst[i] = f2bf(v);
}

// ---------------------------------------------------------------------------
// Prep 2: xT[b][w][c] bf16 = transpose of x[b][c][w] f32.  64x64 LDS tiles.
// grid (W/64, C/64, B)
// ---------------------------------------------------------------------------
__global__ __launch_bounds__(256)
void k_tx(const float* __restrict__ x, unsigned short* __restrict__ xT)
{
  __shared__ float tile[64][68];
  const int b = blockIdx.z, c0 = blockIdx.y * 64, w0 = blockIdx.x * 64;
  const int t = threadIdx.x;
  #pragma unroll
  for (int p = 0; p < 4; ++p) {
    const int r = p * 16 + (t >> 4);
    const float4 v = *(const float4*)&x[((size_t)(b * C_ + c0 + r)) * W_ + w0 + (t & 15) * 4];
    *(float4*)&tile[r][(t & 15) * 4] = v;
  }
  __syncthreads();
  const int w = t >> 2, ch = (t & 3) * 16;
  unsigned short o[16];
  #pragma unroll
  for (int j = 0; j < 16; ++j) o[j] = f2bf(tile[ch + j][w]);
  unsigned short* dst = &xT[((size_t)(b * W_ + w0 + w)) * C_ + c0 + ch];
  *(uint4*)&dst[0] = *(uint4*)&o[0];
  *(uint4*)&dst[8] = *(uint4*)&o[8];
}

// ---------------------------------------------------------------------------
// K1: D[w][ch] = xT[b] (2048x512) @ Wcat^T, tile 128x128, 4 waves (2x2 of 64x64).
// rt=0 -> fT (pooled, transposed out), rt=1 -> gT (transposed out), rt=2,3 -> h (pooled).
// grid (16, 4, 16), 256 thr
// ---------------------------------------------------------------------------
__global__ __launch_bounds__(256)
void k_fgh(const unsigned short* __restrict__ xT, const unsigned short* __restrict__ wcat,
           const float* __restrict__ bfp, const float* __restrict__ bgp,
           const float* __restrict__ bhp,
           unsigned short* __restrict__ fT, unsigned short* __restrict__ gT,
           unsigned short* __restrict__ h)
{
  const int b = blockIdx.z, rt = blockIdx.y, w0 = blockIdx.x * 128;
  const int t = threadIdx.x, l = t & 63, wv = t >> 6;
  const int wr = wv >> 1, wc = wv & 1;
  __shared__ float eps[64][132];

  const unsigned short* A  = xT + ((size_t)(b * W_ + w0 + wr * 64)) * C_;
  const unsigned short* Bt = wcat + (size_t)(rt * 128 + wc * 64) * C_;

  f32x4 acc[4][4];
  #pragma unroll
  for (int i = 0; i < 4; ++i)
    #pragma unroll
    for (int j = 0; j < 4; ++j) acc[i][j] = (f32x4){0.f, 0.f, 0.f, 0.f};

  for (int c0 = 0; c0 < C_; c0 += 32) {
    bf16x8 a[4], bb[4];
    #pragma unroll
    for (int i = 0; i < 4; ++i) a[i]  = ldfrag(A  + (size_t)(i * 16) * C_ + c0, C_);
    #pragma unroll
    for (int j = 0; j < 4; ++j) bb[j] = ldfrag(Bt + (size_t)(j * 16) * C_ + c0, C_);
    #pragma unroll
    for (int i = 0; i < 4; ++i)
      #pragma unroll
      for (int j = 0; j < 4; ++j)
        acc[i][j] = MFMA(a[i], bb[j], acc[i][j]);
  }

  const int lr = l >> 4, lc = l & 15;

  if (rt == 1) {
    // g: no pooling; two half-tile passes through LDS, coalesced gT writes
    #pragma unroll
    for (int p = 0; p < 2; ++p) {
      if (p) __syncthreads();
      if (wr == p) {
        #pragma unroll
        for (int i = 0; i < 4; ++i)
          #pragma unroll
          for (int j = 0; j < 4; ++j)
            #pragma unroll
            for (int r = 0; r < 4; ++r)
              eps[i * 16 + lr * 4 + r][wc * 64 + j * 16 + lc] = acc[i][j][r];
      }
      __syncthreads();
      const int row = t >> 2, chunk = (t & 3) * 32;
      unsigned short o[32];
      #pragma unroll
      for (int j2 = 0; j2 < 32; ++j2) o[j2] = f2bf(eps[row][chunk + j2] + bgp[chunk + j2]);
      unsigned short* dst = &gT[((size_t)(b * W_ + w0 + p * 64 + row)) * C4 + chunk];
      #pragma unroll
      for (int u = 0; u < 4; ++u) *(uint4*)&dst[u * 8] = *(uint4*)&o[u * 8];
    }
  } else {
    // f / h: maxpool pairs of rows (w), stage pooled 64x128 tile
    #pragma unroll
    for (int i = 0; i < 4; ++i)
      #pragma unroll
      for (int j = 0; j < 4; ++j)
        #pragma unroll
        for (int jj = 0; jj < 2; ++jj)
          eps[wr * 32 + i * 8 + lr * 2 + jj][wc * 64 + j * 16 + lc] =
              fmaxf(acc[i][j][2 * jj], acc[i][j][2 * jj + 1]);
    __syncthreads();
    if (rt == 0) {
      // fT[q][c]
      const int row = t >> 2, chunk = (t & 3) * 32;
      unsigned short o[32];
      #pragma unroll
      for (int j2 = 0; j2 < 32; ++j2) o[j2] = f2bf(eps[row][chunk + j2] + bfp[chunk + j2]);
      unsigned short* dst = &fT[((size_t)(b * Q_ + (w0 >> 1) + row)) * C4 + chunk];
      #pragma unroll
      for (int u = 0; u < 4; ++u) *(uint4*)&dst[u * 8] = *(uint4*)&o[u * 8];
    } else {
      // h[ch][q]  (untransposed, rows are channels)
      const int ch = t >> 1, half = (t & 1) * 32;
      const float bv = bhp[(rt - 2) * 128 + ch];
      unsigned short o[32];
      #pragma unroll
      for (int qq = 0; qq < 32; ++qq) o[qq] = f2bf(eps[half + qq][ch] + bv);
      unsigned short* dst = &h[((size_t)(b * C2 + (rt - 2) * 128 + ch)) * Q_ + (w0 >> 1) + half];
      #pragma unroll
      for (int u = 0; u < 4; ++u) *(uint4*)&dst[u * 8] = *(uint4*)&o[u * 8];
    }
  }
}

// ---------------------------------------------------------------------------
// K2: s[q][k] = fT @ gT^T, softmax over k, write beta^T[k][q] bf16.
// q-tile 32, 8 waves each own 256 k.  grid (Q/32, B), 512 thr
// ---------------------------------------------------------------------------
__global__ __launch_bounds__(512)
void k_attn(const unsigned short* __restrict__ fT, const unsigned short* __restrict__ gT,
            unsigned short* __restrict__ bT)
{
  const int b = blockIdx.y, q0 = blockIdx.x * 32;
  const int t = threadIdx.x, l = t & 63, wv = t >> 6;
  const int kbase = wv * 256;
  __shared__ float redm[8][32];
  __shared__ float redl[8][32];

  const unsigned short* A  = fT + (size_t)(b * Q_ + q0) * C4;
  const unsigned short* Bt = gT + (size_t)(b * W_ + kbase) * C4;

  f32x4 acc[2][16];
  #pragma unroll
  for (int qf = 0; qf < 2; ++qf)
    #pragma unroll
    for (int kf = 0; kf < 16; ++kf) acc[qf][kf] = (f32x4){0.f, 0.f, 0.f, 0.f};

  #pragma unroll
  for (int cs = 0; cs < 4; ++cs) {
    const bf16x8 a0 = ldfrag(A + cs * 32, C4);
    const bf16x8 a1 = ldfrag(A + (size_t)16 * C4 + cs * 32, C4);
    #pragma unroll
    for (int kf = 0; kf < 16; ++kf) {
      const bf16x8 bb = ldfrag(Bt + (size_t)(kf * 16) * C4 + cs * 32, C4);
      acc[0][kf] = MFMA(a0, bb, acc[0][kf]);
      acc[1][kf] = MFMA(a1, bb, acc[1][kf]);
    }
  }

  const int lr = l >> 4, lc = l & 15;
  float mx[2][4], sm[2][4];

  // row max (this wave's k range)
  #pragma unroll
  for (int qf = 0; qf < 2; ++qf)
    #pragma unroll
    for (int r = 0; r < 4; ++r) {
      float m = acc[qf][0][r];
      #pragma unroll
      for (int kf = 1; kf < 16; ++kf) m = fmaxf(m, acc[qf][kf][r]);
      #pragma unroll
      for (int d = 1; d < 16; d <<= 1) m = fmaxf(m, __shfl_xor(m, d));
      mx[qf][r] = m;
    }
  if (lc == 0) {
    #pragma unroll
    for (int qf = 0; qf < 2; ++qf)
      #pragma unroll
      for (int r = 0; r < 4; ++r) redm[wv][qf * 16 + lr * 4 + r] = mx[qf][r];
  }
  __syncthreads();
  #pragma unroll
  for (int qf = 0; qf < 2; ++qf)
    #pragma unroll
    for (int r = 0; r < 4; ++r) {
      float m = redm[0][qf * 16 + lr * 4 + r];
      #pragma unroll
      for (int w2 = 1; w2 < 8; ++w2) m = fmaxf(m, redm[w2][qf * 16 + lr * 4 + r]);
      mx[qf][r] = m;
    }

  // exp + row sum
  #pragma unroll
  for (int qf = 0; qf < 2; ++qf)
    #pragma unroll
    for (int r = 0; r < 4; ++r) {
      float s = 0.f;
      #pragma unroll
      for (int kf = 0; kf < 16; ++kf) {
        const float e = __expf(acc[qf][kf][r] - mx[qf][r]);
        acc[qf][kf][r] = e;
        s += e;
      }
      #pragma unroll
      for (int d = 1; d < 16; d <<= 1) s += __shfl_xor(s, d);
      sm[qf][r] = s;
    }
  if (lc == 0) {
    #pragma unroll
    for (int qf = 0; qf < 2; ++qf)
      #pragma unroll
      for (int r = 0; r < 4; ++r) redl[wv][qf * 16 + lr * 4 + r] = sm[qf][r];
  }
  __syncthreads();
  #pragma unroll
  for (int qf = 0; qf < 2; ++qf)
    #pragma unroll
    for (int r = 0; r < 4; ++r) {
      float s = redl[0][qf * 16 + lr * 4 + r];
      #pragma unroll
      for (int w2 = 1; w2 < 8; ++w2) s += redl[w2][qf * 16 + lr * 4 + r];
      sm[qf][r] = 1.f / s;
    }

  // write beta^T[k][q]; 4 lanes x 2 qf chunks fill full 64B rows (L2-merged)
  #pragma unroll
  for (int qf = 0; qf < 2; ++qf)
    #pragma unroll
    for (int kf = 0; kf < 16; ++kf) {
      unsigned short o4[4];
      #pragma unroll
      for (int r = 0; r < 4; ++r) o4[r] = f2bf(acc[qf][kf][r] * sm[qf][r]);
      *(uint2*)&bT[((size_t)(b * W_ + kbase + kf * 16 + lc)) * Q_ + q0 + qf * 16 + lr * 4] =
          *(uint2*)o4;
    }
}

// ---------------------------------------------------------------------------
// K3: o1T[k][c] = beta^T (2048x1024) @ h^T.  M=2048 tiles of 128, N=256 full.
// 8 waves (2x4 of 64x64).  grid (16, B), 512 thr
// ---------------------------------------------------------------------------
__global__ __launch_bounds__(512)
void k_o1(const unsigned short* __restrict__ bT, const unsigned short* __restrict__ h,
          unsigned short* __restrict__ o1T)
{
  const int b = blockIdx.y, m0 = blockIdx.x * 128;
  const int t = threadIdx.x, l = t & 63, wv = t >> 6;
  const int wr = wv >> 2, wc = wv & 3;
  __shared__ unsigned short ot[128][264];

  const unsigned short* A  = bT + (size_t)(b * W_ + m0 + wr * 64) * Q_;
  const unsigned short* Bt = h + (size_t)(b * C2 + wc * 64) * Q_;

  f32x4 acc[4][4];
  #pragma unroll
  for (int i = 0; i < 4; ++i)
    #pragma unroll
    for (int j = 0; j < 4; ++j) acc[i][j] = (f32x4){0.f, 0.f, 0.f, 0.f};

  for (int q0 = 0; q0 < Q_; q0 += 32) {
    bf16x8 a[4], bb[4];
    #pragma unroll
    for (int i = 0; i < 4; ++i) a[i]  = ldfrag(A  + (size_t)(i * 16) * Q_ + q0, Q_);
    #pragma unroll
    for (int j = 0; j < 4; ++j) bb[j] = ldfrag(Bt + (size_t)(j * 16) * Q_ + q0, Q_);
    #pragma unroll
    for (int i = 0; i < 4; ++i)
      #pragma unroll
      for (int j = 0; j < 4; ++j)
        acc[i][j] = MFMA(a[i], bb[j], acc[i][j]);
  }

  const int lr = l >> 4, lc = l & 15;
  #pragma unroll
  for (int i = 0; i < 4; ++i)
    #pragma unroll
    for (int j = 0; j < 4; ++j)
      #pragma unroll
      for (int r = 0; r < 4; ++r)
        ot[wr * 64 + i * 16 + lr * 4 + r][wc * 64 + j * 16 + lc] = f2bf(acc[i][j][r]);
  __syncthreads();
  const int row = t >> 2, chunk = (t & 3) * 64;
  unsigned short* dst = &o1T[((size_t)(b * W_ + m0 + row)) * C2 + chunk];
  #pragma unroll
  for (int u = 0; u < 8; ++u)
    *(uint4*)&dst[u * 8] = *(uint4*)&ot[row][chunk + u * 8];
}

// ---------------------------------------------------------------------------
// K4: out[co][w] = gamma*(o1T @ wa^T + ba) + x.  D rows=w, cols=co.
// grid (16, 4, 16), 256 thr, direct float4 epilogue (no LDS)
// ---------------------------------------------------------------------------
__global__ __launch_bounds__(256)
void k_out(const unsigned short* __restrict__ o1T, const unsigned short* __restrict__ wabf,
           const float* __restrict__ ba, const float* __restrict__ x,
           const float* __restrict__ gamma, float* __restrict__ out)
{
  const int b = blockIdx.z, co0 = blockIdx.y * 128, w0 = blockIdx.x * 128;
  const int t = threadIdx.x, l = t & 63, wv = t >> 6;
  const int wr = wv >> 1, wc = wv & 1;

  const unsigned short* A  = o1T + (size_t)(b * W_ + w0 + wr * 64) * C2;
  const unsigned short* Bt = wabf + (size_t)(co0 + wc * 64) * C2;

  f32x4 acc[4][4];
  #pragma unroll
  for (int i = 0; i < 4; ++i)
    #pragma unroll
    for (int j = 0; j < 4; ++j) acc[i][j] = (f32x4){0.f, 0.f, 0.f, 0.f};

  for (int c0 = 0; c0 < C2; c0 += 32) {
    bf16x8 a[4], bb[4];
    #pragma unroll
    for (int i = 0; i < 4; ++i) a[i]  = ldfrag(A  + (size_t)(i * 16) * C2 + c0, C2);
    #pragma unroll
    for (int j = 0; j < 4; ++j) bb[j] = ldfrag(Bt + (size_t)(j * 16) * C2 + c0, C2);
    #pragma unroll
    for (int i = 0; i < 4; ++i)
      #pragma unroll
      for (int j = 0; j < 4; ++j)
        acc[i][j] = MFMA(a[i], bb[j], acc[i][j]);
  }

  const float gm = gamma[0];
  const int lr = l >> 4, lc = l & 15;
  #pragma unroll
  for (int i = 0; i < 4; ++i)
    #pragma unroll
    for (int j = 0; j < 4; ++j) {
      const int co = co0 + wc * 64 + j * 16 + lc;
      const int w  = w0 + wr * 64 + i * 16 + lr * 4;
      const float bb2 = ba[co];
      const size_t idx = ((size_t)(b * C_ + co)) * W_ + w;
      const float4 xv = *(const float4*)&x[idx];
      float4 ov;
      ov.x = gm * (acc[i][j][0] + bb2) + xv.x;
      ov.y = gm * (acc[i][j][1] + bb2) + xv.y;
      ov.z = gm * (acc[i][j][2] + bb2) + xv.z;
      ov.w = gm * (acc[i][j][3] + bb2) + xv.w;
      *(float4*)&out[idx] = ov;
    }
}

// ---------------------------------------------------------------------------
extern "C" void kernel_launch(void* const* d_in, const int* in_sizes, int n_in,
                              void* d_out, int out_size, void* d_ws, size_t ws_size,
                              hipStream_t stream)
{
  const float* x     = (const float*)d_in[0];
  const float* wf    = (const float*)d_in[1];
  const float* bfp   = (const float*)d_in[2];
  const float* wg    = (const float*)d_in[3];
  const float* bgp   = (const float*)d_in[4];
  const float* wh    = (const float*)d_in[5];
  const float* bhp   = (const float*)d_in[6];
  const float* wa    = (const float*)d_in[7];
  const float* ba    = (const float*)d_in[8];
  const float* gamma = (const float*)d_in[9];
  float* out = (float*)d_out;

  unsigned short* ws = (unsigned short*)d_ws;
  size_t off = 0;
  unsigned short* wbf = ws + off;  off += 393216;                    // weights bf16
  unsigned short* xT  = ws + off;  off += (size_t)B_ * W_ * C_;      // 32 MB
  unsigned short* fT  = ws + off;  off += (size_t)B_ * Q_ * C4;      //  4 MB
  unsigned short* gT  = ws + off;  off += (size_t)B_ * W_ * C4;      //  8 MB
  unsigned short* h   = ws + off;  off += (size_t)B_ * C2 * Q_;      //  8 MB
  unsigned short* bT  = ws + off;  off += (size_t)B_ * W_ * Q_;      // 64 MB
  unsigned short* o1T = ws + off;  off += (size_t)B_ * W_ * C2;      // 16 MB
  unsigned short* wabf = wbf + 262144;

  k_cvt<<<dim3(1536), dim3(256), 0, stream>>>(wf, wg, wh, wa, wbf);
  k_tx<<<dim3(W_ / 64, C_ / 64, B_), dim3(256), 0, stream>>>(x, xT);
  k_fgh<<<dim3(W_ / 128, 4, B_), dim3(256), 0, stream>>>(xT, wbf, bfp, bgp, bhp, fT, gT, h);
  k_attn<<<dim3(Q_ / 32, B_), dim3(512), 0, stream>>>(fT, gT, bT);
  k_o1<<<dim3(W_ / 128, B_), dim3(512), 0, stream>>>(bT, h, o1T);
  k_out<<<dim3(W_ / 128, 4, B_), dim3(256), 0, stream>>>(o1T, wabf, ba, x, gamma, out);
}

// Round 5
// 283.076 us; speedup vs baseline: 2.3581x; 1.0181x over previous
//
#include <hip/hip_runtime.h>

#define DI __device__ __forceinline__

constexpr int B_ = 16;
constexpr int C_ = 512;
constexpr int W_ = 2048;
constexpr int C4 = 128;
constexpr int C2 = 256;
constexpr int Q_ = 1024;

typedef short bf16x8 __attribute__((ext_vector_type(8)));
typedef float f32x4 __attribute__((ext_vector_type(4)));

DI f32x4 MFMA(bf16x8 a, bf16x8 b, f32x4 c) {
  return __builtin_amdgcn_mfma_f32_16x16x32_bf16(a, b, c, 0, 0, 0);
}

DI unsigned short f2bf(float v) {
  union { float f; unsigned int i; } c; c.f = v;
  return (unsigned short)((c.i + 0x7FFFu + ((c.i >> 16) & 1u)) >> 16);
}

// Fragment load from row-major bf16 matrix (leading dim ld, in elements).
// lane l -> row (l&15), k-offset (l>>4)*8  (16B contiguous per lane).
DI bf16x8 ldfrag(const unsigned short* p, int ld) {
  const int l = threadIdx.x & 63;
  return *(const bf16x8*)(p + (size_t)(l & 15) * ld + ((l >> 4) << 3));
}

// ---------------------------------------------------------------------------
// Prep 1: convert weights to bf16.  dst layout: [wf 64K][wg 64K][wh 128K][wa 128K]
// ---------------------------------------------------------------------------
__global__ __launch_bounds__(256)
void k_cvt(const float* __restrict__ wf, const float* __restrict__ wg,
           const float* __restrict__ wh, const float* __restrict__ wa,
           unsigned short* __restrict__ dst)
{
  const int i = blockIdx.x * 256 + threadIdx.x;   // grid covers 393216
  float v;
  if (i < 65536)        v = wf[i];
  else if (i < 131072)  v = wg[i - 65536];
  else if (i < 262144)  v = wh[i - 131072];
  else                  v = wa[i - 262144];
  dst[i] = f2bf(v);
}

// ---------------------------------------------------------------------------
// Prep 2: xT[b][w][c] bf16 = transpose of x[b][c][w] f32.  64x64 LDS tiles.
// grid (W/64, C/64, B)
// ---------------------------------------------------------------------------
__global__ __launch_bounds__(256)
void k_tx(const float* __restrict__ x, unsigned short* __restrict__ xT)
{
  __shared__ float tile[64][68];
  const int b = blockIdx.z, c0 = blockIdx.y * 64, w0 = blockIdx.x * 64;
  const int t = threadIdx.x;
  #pragma unroll
  for (int p = 0; p < 4; ++p) {
    const int r = p * 16 + (t >> 4);
    const float4 v = *(const float4*)&x[((size_t)(b * C_ + c0 + r)) * W_ + w0 + (t & 15) * 4];
    *(float4*)&tile[r][(t & 15) * 4] = v;
  }
  __syncthreads();
  const int w = t >> 2, ch = (t & 3) * 16;
  unsigned short o[16];
  #pragma unroll
  for (int j = 0; j < 16; ++j) o[j] = f2bf(tile[ch + j][w]);
  unsigned short* dst = &xT[((size_t)(b * W_ + w0 + w)) * C_ + c0 + ch];
  *(uint4*)&dst[0] = *(uint4*)&o[0];
  *(uint4*)&dst[8] = *(uint4*)&o[8];
}

// ---------------------------------------------------------------------------
// K1: D[w][ch] = xT[b] (2048x512) @ Wcat^T, tile 128x128, 4 waves (2x2 of 64x64).
// rt=0 -> fT (pooled, transposed out), rt=1 -> gT (transposed out), rt=2,3 -> h (pooled).
// grid (16, 4, 16), 256 thr
// ---------------------------------------------------------------------------
__global__ __launch_bounds__(256)
void k_fgh(const unsigned short* __restrict__ xT, const unsigned short* __restrict__ wcat,
           const float* __restrict__ bfp, const float* __restrict__ bgp,
           const float* __restrict__ bhp,
           unsigned short* __restrict__ fT, unsigned short* __restrict__ gT,
           unsigned short* __restrict__ h)
{
  const int b = blockIdx.z, rt = blockIdx.y, w0 = blockIdx.x * 128;
  const int t = threadIdx.x, l = t & 63, wv = t >> 6;
  const int wr = wv >> 1, wc = wv & 1;
  __shared__ float eps[64][132];

  const unsigned short* A  = xT + ((size_t)(b * W_ + w0 + wr * 64)) * C_;
  const unsigned short* Bt = wcat + (size_t)(rt * 128 + wc * 64) * C_;

  f32x4 acc[4][4];
  #pragma unroll
  for (int i = 0; i < 4; ++i)
    #pragma unroll
    for (int j = 0; j < 4; ++j) acc[i][j] = (f32x4){0.f, 0.f, 0.f, 0.f};

  for (int c0 = 0; c0 < C_; c0 += 32) {
    bf16x8 a[4], bb[4];
    #pragma unroll
    for (int i = 0; i < 4; ++i) a[i]  = ldfrag(A  + (size_t)(i * 16) * C_ + c0, C_);
    #pragma unroll
    for (int j = 0; j < 4; ++j) bb[j] = ldfrag(Bt + (size_t)(j * 16) * C_ + c0, C_);
    #pragma unroll
    for (int i = 0; i < 4; ++i)
      #pragma unroll
      for (int j = 0; j < 4; ++j)
        acc[i][j] = MFMA(a[i], bb[j], acc[i][j]);
  }

  const int lr = l >> 4, lc = l & 15;

  if (rt == 1) {
    // g: no pooling; two half-tile passes through LDS, coalesced gT writes
    #pragma unroll
    for (int p = 0; p < 2; ++p) {
      if (p) __syncthreads();
      if (wr == p) {
        #pragma unroll
        for (int i = 0; i < 4; ++i)
          #pragma unroll
          for (int j = 0; j < 4; ++j)
            #pragma unroll
            for (int r = 0; r < 4; ++r)
              eps[i * 16 + lr * 4 + r][wc * 64 + j * 16 + lc] = acc[i][j][r];
      }
      __syncthreads();
      const int row = t >> 2, chunk = (t & 3) * 32;
      unsigned short o[32];
      #pragma unroll
      for (int j2 = 0; j2 < 32; ++j2) o[j2] = f2bf(eps[row][chunk + j2] + bgp[chunk + j2]);
      unsigned short* dst = &gT[((size_t)(b * W_ + w0 + p * 64 + row)) * C4 + chunk];
      #pragma unroll
      for (int u = 0; u < 4; ++u) *(uint4*)&dst[u * 8] = *(uint4*)&o[u * 8];
    }
  } else {
    // f / h: maxpool pairs of rows (w), stage pooled 64x128 tile
    #pragma unroll
    for (int i = 0; i < 4; ++i)
      #pragma unroll
      for (int j = 0; j < 4; ++j)
        #pragma unroll
        for (int jj = 0; jj < 2; ++jj)
          eps[wr * 32 + i * 8 + lr * 2 + jj][wc * 64 + j * 16 + lc] =
              fmaxf(acc[i][j][2 * jj], acc[i][j][2 * jj + 1]);
    __syncthreads();
    if (rt == 0) {
      // fT[q][c]
      const int row = t >> 2, chunk = (t & 3) * 32;
      unsigned short o[32];
      #pragma unroll
      for (int j2 = 0; j2 < 32; ++j2) o[j2] = f2bf(eps[row][chunk + j2] + bfp[chunk + j2]);
      unsigned short* dst = &fT[((size_t)(b * Q_ + (w0 >> 1) + row)) * C4 + chunk];
      #pragma unroll
      for (int u = 0; u < 4; ++u) *(uint4*)&dst[u * 8] = *(uint4*)&o[u * 8];
    } else {
      // h[ch][q]  (untransposed, rows are channels)
      const int ch = t >> 1, half = (t & 1) * 32;
      const float bv = bhp[(rt - 2) * 128 + ch];
      unsigned short o[32];
      #pragma unroll
      for (int qq = 0; qq < 32; ++qq) o[qq] = f2bf(eps[half + qq][ch] + bv);
      unsigned short* dst = &h[((size_t)(b * C2 + (rt - 2) * 128 + ch)) * Q_ + (w0 >> 1) + half];
      #pragma unroll
      for (int u = 0; u < 4; ++u) *(uint4*)&dst[u * 8] = *(uint4*)&o[u * 8];
    }
  }
}

// ---------------------------------------------------------------------------
// K2: s[q][k] = fT @ gT^T, softmax over k, write beta^T[k][q] bf16.
// q-tile 32; 16 waves each own 128 k (8 kf) -> acc 64 f32/lane, 4 waves/SIMD.
// grid (Q/32, B), 1024 thr
// ---------------------------------------------------------------------------
__global__ __launch_bounds__(1024)
void k_attn(const unsigned short* __restrict__ fT, const unsigned short* __restrict__ gT,
            unsigned short* __restrict__ bT)
{
  const int b = blockIdx.y, q0 = blockIdx.x * 32;
  const int t = threadIdx.x, l = t & 63, wv = t >> 6;     // wv 0..15
  const int kbase = wv * 128;
  __shared__ float redm[16][32];
  __shared__ float redl[16][32];

  const unsigned short* A  = fT + (size_t)(b * Q_ + q0) * C4;
  const unsigned short* Bt = gT + (size_t)(b * W_ + kbase) * C4;

  f32x4 acc[2][8];
  #pragma unroll
  for (int qf = 0; qf < 2; ++qf)
    #pragma unroll
    for (int kf = 0; kf < 8; ++kf) acc[qf][kf] = (f32x4){0.f, 0.f, 0.f, 0.f};

  #pragma unroll
  for (int cs = 0; cs < 4; ++cs) {
    const bf16x8 a0 = ldfrag(A + cs * 32, C4);
    const bf16x8 a1 = ldfrag(A + (size_t)16 * C4 + cs * 32, C4);
    #pragma unroll
    for (int kf = 0; kf < 8; ++kf) {
      const bf16x8 bb = ldfrag(Bt + (size_t)(kf * 16) * C4 + cs * 32, C4);
      acc[0][kf] = MFMA(a0, bb, acc[0][kf]);
      acc[1][kf] = MFMA(a1, bb, acc[1][kf]);
    }
  }

  const int lr = l >> 4, lc = l & 15;
  float mx[2][4], sm[2][4];

  // row max (this wave's k range)
  #pragma unroll
  for (int qf = 0; qf < 2; ++qf)
    #pragma unroll
    for (int r = 0; r < 4; ++r) {
      float m = acc[qf][0][r];
      #pragma unroll
      for (int kf = 1; kf < 8; ++kf) m = fmaxf(m, acc[qf][kf][r]);
      #pragma unroll
      for (int d = 1; d < 16; d <<= 1) m = fmaxf(m, __shfl_xor(m, d));
      mx[qf][r] = m;
    }
  if (lc == 0) {
    #pragma unroll
    for (int qf = 0; qf < 2; ++qf)
      #pragma unroll
      for (int r = 0; r < 4; ++r) redm[wv][qf * 16 + lr * 4 + r] = mx[qf][r];
  }
  __syncthreads();
  #pragma unroll
  for (int qf = 0; qf < 2; ++qf)
    #pragma unroll
    for (int r = 0; r < 4; ++r) {
      float m = redm[0][qf * 16 + lr * 4 + r];
      #pragma unroll
      for (int w2 = 1; w2 < 16; ++w2) m = fmaxf(m, redm[w2][qf * 16 + lr * 4 + r]);
      mx[qf][r] = m;
    }

  // exp + row sum
  #pragma unroll
  for (int qf = 0; qf < 2; ++qf)
    #pragma unroll
    for (int r = 0; r < 4; ++r) {
      float s = 0.f;
      #pragma unroll
      for (int kf = 0; kf < 8; ++kf) {
        const float e = __expf(acc[qf][kf][r] - mx[qf][r]);
        acc[qf][kf][r] = e;
        s += e;
      }
      #pragma unroll
      for (int d = 1; d < 16; d <<= 1) s += __shfl_xor(s, d);
      sm[qf][r] = s;
    }
  if (lc == 0) {
    #pragma unroll
    for (int qf = 0; qf < 2; ++qf)
      #pragma unroll
      for (int r = 0; r < 4; ++r) redl[wv][qf * 16 + lr * 4 + r] = sm[qf][r];
  }
  __syncthreads();
  #pragma unroll
  for (int qf = 0; qf < 2; ++qf)
    #pragma unroll
    for (int r = 0; r < 4; ++r) {
      float s = redl[0][qf * 16 + lr * 4 + r];
      #pragma unroll
      for (int w2 = 1; w2 < 16; ++w2) s += redl[w2][qf * 16 + lr * 4 + r];
      sm[qf][r] = 1.f / s;
    }

  // write beta^T[k][q]; lanes cover 16 rows x 32B chunks
  #pragma unroll
  for (int qf = 0; qf < 2; ++qf)
    #pragma unroll
    for (int kf = 0; kf < 8; ++kf) {
      unsigned short o4[4];
      #pragma unroll
      for (int r = 0; r < 4; ++r) o4[r] = f2bf(acc[qf][kf][r] * sm[qf][r]);
      *(uint2*)&bT[((size_t)(b * W_ + kbase + kf * 16 + lc)) * Q_ + q0 + qf * 16 + lr * 4] =
          *(uint2*)o4;
    }
}

// ---------------------------------------------------------------------------
// K3: o1T[k][c] = beta^T (2048x1024) @ h^T.  M=2048 tiles of 128, N=256 full.
// 8 waves (2x4 of 64x64).  grid (16, B), 512 thr
// ---------------------------------------------------------------------------
__global__ __launch_bounds__(512)
void k_o1(const unsigned short* __restrict__ bT, const unsigned short* __restrict__ h,
          unsigned short* __restrict__ o1T)
{
  const int b = blockIdx.y, m0 = blockIdx.x * 128;
  const int t = threadIdx.x, l = t & 63, wv = t >> 6;
  const int wr = wv >> 2, wc = wv & 3;
  __shared__ unsigned short ot[128][264];

  const unsigned short* A  = bT + (size_t)(b * W_ + m0 + wr * 64) * Q_;
  const unsigned short* Bt = h + (size_t)(b * C2 + wc * 64) * Q_;

  f32x4 acc[4][4];
  #pragma unroll
  for (int i = 0; i < 4; ++i)
    #pragma unroll
    for (int j = 0; j < 4; ++j) acc[i][j] = (f32x4){0.f, 0.f, 0.f, 0.f};

  for (int q0 = 0; q0 < Q_; q0 += 32) {
    bf16x8 a[4], bb[4];
    #pragma unroll
    for (int i = 0; i < 4; ++i) a[i]  = ldfrag(A  + (size_t)(i * 16) * Q_ + q0, Q_);
    #pragma unroll
    for (int j = 0; j < 4; ++j) bb[j] = ldfrag(Bt + (size_t)(j * 16) * Q_ + q0, Q_);
    #pragma unroll
    for (int i = 0; i < 4; ++i)
      #pragma unroll
      for (int j = 0; j < 4; ++j)
        acc[i][j] = MFMA(a[i], bb[j], acc[i][j]);
  }

  const int lr = l >> 4, lc = l & 15;
  #pragma unroll
  for (int i = 0; i < 4; ++i)
    #pragma unroll
    for (int j = 0; j < 4; ++j)
      #pragma unroll
      for (int r = 0; r < 4; ++r)
        ot[wr * 64 + i * 16 + lr * 4 + r][wc * 64 + j * 16 + lc] = f2bf(acc[i][j][r]);
  __syncthreads();
  const int row = t >> 2, chunk = (t & 3) * 64;
  unsigned short* dst = &o1T[((size_t)(b * W_ + m0 + row)) * C2 + chunk];
  #pragma unroll
  for (int u = 0; u < 8; ++u)
    *(uint4*)&dst[u * 8] = *(uint4*)&ot[row][chunk + u * 8];
}

// ---------------------------------------------------------------------------
// K4: out[co][w] = gamma*(o1T @ wa^T + ba) + x.  D rows=w, cols=co.
// grid (16, 4, 16), 256 thr, direct float4 epilogue (no LDS)
// ---------------------------------------------------------------------------
__global__ __launch_bounds__(256)
void k_out(const unsigned short* __restrict__ o1T, const unsigned short* __restrict__ wabf,
           const float* __restrict__ ba, const float* __restrict__ x,
           const float* __restrict__ gamma, float* __restrict__ out)
{
  const int b = blockIdx.z, co0 = blockIdx.y * 128, w0 = blockIdx.x * 128;
  const int t = threadIdx.x, l = t & 63, wv = t >> 6;
  const int wr = wv >> 1, wc = wv & 1;

  const unsigned short* A  = o1T + (size_t)(b * W_ + w0 + wr * 64) * C2;
  const unsigned short* Bt = wabf + (size_t)(co0 + wc * 64) * C2;

  f32x4 acc[4][4];
  #pragma unroll
  for (int i = 0; i < 4; ++i)
    #pragma unroll
    for (int j = 0; j < 4; ++j) acc[i][j] = (f32x4){0.f, 0.f, 0.f, 0.f};

  for (int c0 = 0; c0 < C2; c0 += 32) {
    bf16x8 a[4], bb[4];
    #pragma unroll
    for (int i = 0; i < 4; ++i) a[i]  = ldfrag(A  + (size_t)(i * 16) * C2 + c0, C2);
    #pragma unroll
    for (int j = 0; j < 4; ++j) bb[j] = ldfrag(Bt + (size_t)(j * 16) * C2 + c0, C2);
    #pragma unroll
    for (int i = 0; i < 4; ++i)
      #pragma unroll
      for (int j = 0; j < 4; ++j)
        acc[i][j] = MFMA(a[i], bb[j], acc[i][j]);
  }

  const float gm = gamma[0];
  const int lr = l >> 4, lc = l & 15;
  #pragma unroll
  for (int i = 0; i < 4; ++i)
    #pragma unroll
    for (int j = 0; j < 4; ++j) {
      const int co = co0 + wc * 64 + j * 16 + lc;
      const int w  = w0 + wr * 64 + i * 16 + lr * 4;
      const float bb2 = ba[co];
      const size_t idx = ((size_t)(b * C_ + co)) * W_ + w;
      const float4 xv = *(const float4*)&x[idx];
      float4 ov;
      ov.x = gm * (acc[i][j][0] + bb2) + xv.x;
      ov.y = gm * (acc[i][j][1] + bb2) + xv.y;
      ov.z = gm * (acc[i][j][2] + bb2) + xv.z;
      ov.w = gm * (acc[i][j][3] + bb2) + xv.w;
      *(float4*)&out[idx] = ov;
    }
}

// ---------------------------------------------------------------------------
extern "C" void kernel_launch(void* const* d_in, const int* in_sizes, int n_in,
                              void* d_out, int out_size, void* d_ws, size_t ws_size,
                              hipStream_t stream)
{
  const float* x     = (const float*)d_in[0];
  const float* wf    = (const float*)d_in[1];
  const float* bfp   = (const float*)d_in[2];
  const float* wg    = (const float*)d_in[3];
  const float* bgp   = (const float*)d_in[4];
  const float* wh    = (const float*)d_in[5];
  const float* bhp   = (const float*)d_in[6];
  const float* wa    = (const float*)d_in[7];
  const float* ba    = (const float*)d_in[8];
  const float* gamma = (const float*)d_in[9];
  float* out = (float*)d_out;

  unsigned short* ws = (unsigned short*)d_ws;
  size_t off = 0;
  unsigned short* wbf = ws + off;  off += 393216;                    // weights bf16
  unsigned short* xT  = ws + off;  off += (size_t)B_ * W_ * C_;      // 32 MB
  unsigned short* fT  = ws + off;  off += (size_t)B_ * Q_ * C4;      //  4 MB
  unsigned short* gT  = ws + off;  off += (size_t)B_ * W_ * C4;      //  8 MB
  unsigned short* h   = ws + off;  off += (size_t)B_ * C2 * Q_;      //  8 MB
  unsigned short* bT  = ws + off;  off += (size_t)B_ * W_ * Q_;      // 64 MB
  unsigned short* o1T = ws + off;  off += (size_t)B_ * W_ * C2;      // 16 MB
  unsigned short* wabf = wbf + 262144;

  k_cvt<<<dim3(1536), dim3(256), 0, stream>>>(wf, wg, wh, wa, wbf);
  k_tx<<<dim3(W_ / 64, C_ / 64, B_), dim3(256), 0, stream>>>(x, xT);
  k_fgh<<<dim3(W_ / 128, 4, B_), dim3(256), 0, stream>>>(xT, wbf, bfp, bgp, bhp, fT, gT, h);
  k_attn<<<dim3(Q_ / 32, B_), dim3(1024), 0, stream>>>(fT, gT, bT);
  k_o1<<<dim3(W_ / 128, B_), dim3(512), 0, stream>>>(bT, h, o1T);
  k_out<<<dim3(W_ / 128, 4, B_), dim3(256), 0, stream>>>(o1T, wabf, ba, x, gamma, out);
}

// Round 6
// 211.122 us; speedup vs baseline: 3.1617x; 1.3408x over previous
//
#include <hip/hip_runtime.h>

#define DI __device__ __forceinline__

constexpr int B_ = 16;
constexpr int C_ = 512;
constexpr int W_ = 2048;
constexpr int C4 = 128;
constexpr int C2 = 256;
constexpr int Q_ = 1024;

typedef short bf16x8 __attribute__((ext_vector_type(8)));
typedef float f32x4 __attribute__((ext_vector_type(4)));

DI f32x4 MFMA(bf16x8 a, bf16x8 b, f32x4 c) {
  return __builtin_amdgcn_mfma_f32_16x16x32_bf16(a, b, c, 0, 0, 0);
}

DI unsigned short f2bf(float v) {
  union { float f; unsigned int i; } c; c.f = v;
  return (unsigned short)((c.i + 0x7FFFu + ((c.i >> 16) & 1u)) >> 16);
}

DI bf16x8 ldfrag(const unsigned short* p, int ld) {
  const int l = threadIdx.x & 63;
  return *(const bf16x8*)(p + (size_t)(l & 15) * ld + ((l >> 4) << 3));
}

// async 16B global->LDS; lds dest is wave-uniform base + lane*16
DI void gload16(const unsigned short* g, unsigned short* l) {
  __builtin_amdgcn_global_load_lds((const __attribute__((address_space(1))) void*)(g),
                                   (__attribute__((address_space(3))) void*)(l), 16, 0, 0);
}

// ---------------------------------------------------------------------------
// Prep 1: weights -> bf16.  [wf 64K][wg 64K][wh 128K][wa 128K]
// ---------------------------------------------------------------------------
__global__ __launch_bounds__(256)
void k_cvt(const float* __restrict__ wf, const float* __restrict__ wg,
           const float* __restrict__ wh, const float* __restrict__ wa,
           unsigned short* __restrict__ dst)
{
  const int i = blockIdx.x * 256 + threadIdx.x;
  float v;
  if (i < 65536)        v = wf[i];
  else if (i < 131072)  v = wg[i - 65536];
  else if (i < 262144)  v = wh[i - 131072];
  else                  v = wa[i - 262144];
  dst[i] = f2bf(v);
}

// ---------------------------------------------------------------------------
// Prep 2: xT[b][w][c] bf16 = transpose of x[b][c][w] f32.
// ---------------------------------------------------------------------------
__global__ __launch_bounds__(256)
void k_tx(const float* __restrict__ x, unsigned short* __restrict__ xT)
{
  __shared__ float tile[64][68];
  const int b = blockIdx.z, c0 = blockIdx.y * 64, w0 = blockIdx.x * 64;
  const int t = threadIdx.x;
  #pragma unroll
  for (int p = 0; p < 4; ++p) {
    const int r = p * 16 + (t >> 4);
    const float4 v = *(const float4*)&x[((size_t)(b * C_ + c0 + r)) * W_ + w0 + (t & 15) * 4];
    *(float4*)&tile[r][(t & 15) * 4] = v;
  }
  __syncthreads();
  const int w = t >> 2, ch = (t & 3) * 16;
  unsigned short o[16];
  #pragma unroll
  for (int j = 0; j < 16; ++j) o[j] = f2bf(tile[ch + j][w]);
  unsigned short* dst = &xT[((size_t)(b * W_ + w0 + w)) * C_ + c0 + ch];
  *(uint4*)&dst[0] = *(uint4*)&o[0];
  *(uint4*)&dst[8] = *(uint4*)&o[8];
}

// ---------------------------------------------------------------------------
// K1: m97-style LDS-staged GEMM. Tile 128(w) x 128(ch), BK=32, 4 waves 2x2.
// rt=0 -> fT (pooled,T), rt=1 -> gT (T), rt=2,3 -> h (pooled). grid (16,4,16)
// ---------------------------------------------------------------------------
__global__ __launch_bounds__(256)
void k_fgh(const unsigned short* __restrict__ xT, const unsigned short* __restrict__ wcat,
           const float* __restrict__ bfp, const float* __restrict__ bgp,
           const float* __restrict__ bhp,
           unsigned short* __restrict__ fT, unsigned short* __restrict__ gT,
           unsigned short* __restrict__ h)
{
  const int b = blockIdx.z, rt = blockIdx.y, w0 = blockIdx.x * 128;
  const int t = threadIdx.x, l = t & 63, wv = t >> 6;
  const int wr = wv >> 1, wc = wv & 1;

  __shared__ __align__(16) char smraw[33792];   // staging 32KB | epilogue 64x132 f32
  unsigned short* stg = (unsigned short*)smraw; // [buf][ab][4096]
  float (*eps)[132] = (float(*)[132])smraw;

  const unsigned short* Abase = xT + ((size_t)(b * W_ + w0)) * C_;
  const unsigned short* Bbase = wcat + (size_t)(rt * 128) * C_;

  const int wub = (t & 192) * 8;          // wave-uniform lds elem base per instr block
  const int r0s = t >> 2, kcs = (t & 3) * 8;

  auto STAGE = [&](int buf, int c0) {
    #pragma unroll
    for (int i = 0; i < 2; ++i) {
      const int row = i * 64 + r0s;
      gload16(Abase + (size_t)row * C_ + c0 + kcs, stg + (buf * 2 + 0) * 4096 + i * 2048 + wub);
      gload16(Bbase + (size_t)row * C_ + c0 + kcs, stg + (buf * 2 + 1) * 4096 + i * 2048 + wub);
    }
  };

  f32x4 acc[4][4];
  #pragma unroll
  for (int i = 0; i < 4; ++i)
    #pragma unroll
    for (int j = 0; j < 4; ++j) acc[i][j] = (f32x4){0.f, 0.f, 0.f, 0.f};

  STAGE(0, 0);
  for (int kt = 0; kt < 16; ++kt) {
    const int cur = kt & 1;
    __syncthreads();                       // drains vmcnt -> buf[cur] ready
    if (kt + 1 < 16) STAGE(cur ^ 1, (kt + 1) * 32);
    const unsigned short* As = stg + (cur * 2 + 0) * 4096;
    const unsigned short* Bs = stg + (cur * 2 + 1) * 4096;
    bf16x8 a[4], bb[4];
    #pragma unroll
    for (int i = 0; i < 4; ++i)
      a[i] = *(const bf16x8*)&As[(wr * 64 + i * 16 + (l & 15)) * 32 + ((l >> 4) << 3)];
    #pragma unroll
    for (int j = 0; j < 4; ++j)
      bb[j] = *(const bf16x8*)&Bs[(wc * 64 + j * 16 + (l & 15)) * 32 + ((l >> 4) << 3)];
    #pragma unroll
    for (int i = 0; i < 4; ++i)
      #pragma unroll
      for (int j = 0; j < 4; ++j)
        acc[i][j] = MFMA(a[i], bb[j], acc[i][j]);
  }
  __syncthreads();                          // staging arena -> epilogue overlay

  const int lr = l >> 4, lc = l & 15;

  if (rt == 1) {
    #pragma unroll
    for (int p = 0; p < 2; ++p) {
      if (p) __syncthreads();
      if (wr == p) {
        #pragma unroll
        for (int i = 0; i < 4; ++i)
          #pragma unroll
          for (int j = 0; j < 4; ++j)
            #pragma unroll
            for (int r = 0; r < 4; ++r)
              eps[i * 16 + lr * 4 + r][wc * 64 + j * 16 + lc] = acc[i][j][r];
      }
      __syncthreads();
      const int row = t >> 2, chunk = (t & 3) * 32;
      unsigned short o[32];
      #pragma unroll
      for (int j2 = 0; j2 < 32; ++j2) o[j2] = f2bf(eps[row][chunk + j2] + bgp[chunk + j2]);
      unsigned short* dst = &gT[((size_t)(b * W_ + w0 + p * 64 + row)) * C4 + chunk];
      #pragma unroll
      for (int u = 0; u < 4; ++u) *(uint4*)&dst[u * 8] = *(uint4*)&o[u * 8];
    }
  } else {
    #pragma unroll
    for (int i = 0; i < 4; ++i)
      #pragma unroll
      for (int j = 0; j < 4; ++j)
        #pragma unroll
        for (int jj = 0; jj < 2; ++jj)
          eps[wr * 32 + i * 8 + lr * 2 + jj][wc * 64 + j * 16 + lc] =
              fmaxf(acc[i][j][2 * jj], acc[i][j][2 * jj + 1]);
    __syncthreads();
    if (rt == 0) {
      const int row = t >> 2, chunk = (t & 3) * 32;
      unsigned short o[32];
      #pragma unroll
      for (int j2 = 0; j2 < 32; ++j2) o[j2] = f2bf(eps[row][chunk + j2] + bfp[chunk + j2]);
      unsigned short* dst = &fT[((size_t)(b * Q_ + (w0 >> 1) + row)) * C4 + chunk];
      #pragma unroll
      for (int u = 0; u < 4; ++u) *(uint4*)&dst[u * 8] = *(uint4*)&o[u * 8];
    } else {
      const int ch = t >> 1, half = (t & 1) * 32;
      const float bv = bhp[(rt - 2) * 128 + ch];
      unsigned short o[32];
      #pragma unroll
      for (int qq = 0; qq < 32; ++qq) o[qq] = f2bf(eps[half + qq][ch] + bv);
      unsigned short* dst = &h[((size_t)(b * C2 + (rt - 2) * 128 + ch)) * Q_ + (w0 >> 1) + half];
      #pragma unroll
      for (int u = 0; u < 4; ++u) *(uint4*)&dst[u * 8] = *(uint4*)&o[u * 8];
    }
  }
}

// ---------------------------------------------------------------------------
// K2: s = fT @ gT^T, softmax over k, beta^T bf16. (unchanged this round)
// ---------------------------------------------------------------------------
__global__ __launch_bounds__(1024)
void k_attn(const unsigned short* __restrict__ fT, const unsigned short* __restrict__ gT,
            unsigned short* __restrict__ bT)
{
  const int b = blockIdx.y, q0 = blockIdx.x * 32;
  const int t = threadIdx.x, l = t & 63, wv = t >> 6;
  const int kbase = wv * 128;
  __shared__ float redm[16][32];
  __shared__ float redl[16][32];

  const unsigned short* A  = fT + (size_t)(b * Q_ + q0) * C4;
  const unsigned short* Bt = gT + (size_t)(b * W_ + kbase) * C4;

  f32x4 acc[2][8];
  #pragma unroll
  for (int qf = 0; qf < 2; ++qf)
    #pragma unroll
    for (int kf = 0; kf < 8; ++kf) acc[qf][kf] = (f32x4){0.f, 0.f, 0.f, 0.f};

  #pragma unroll
  for (int cs = 0; cs < 4; ++cs) {
    const bf16x8 a0 = ldfrag(A + cs * 32, C4);
    const bf16x8 a1 = ldfrag(A + (size_t)16 * C4 + cs * 32, C4);
    #pragma unroll
    for (int kf = 0; kf < 8; ++kf) {
      const bf16x8 bb = ldfrag(Bt + (size_t)(kf * 16) * C4 + cs * 32, C4);
      acc[0][kf] = MFMA(a0, bb, acc[0][kf]);
      acc[1][kf] = MFMA(a1, bb, acc[1][kf]);
    }
  }

  const int lr = l >> 4, lc = l & 15;
  float mx[2][4], sm[2][4];

  #pragma unroll
  for (int qf = 0; qf < 2; ++qf)
    #pragma unroll
    for (int r = 0; r < 4; ++r) {
      float m = acc[qf][0][r];
      #pragma unroll
      for (int kf = 1; kf < 8; ++kf) m = fmaxf(m, acc[qf][kf][r]);
      #pragma unroll
      for (int d = 1; d < 16; d <<= 1) m = fmaxf(m, __shfl_xor(m, d));
      mx[qf][r] = m;
    }
  if (lc == 0) {
    #pragma unroll
    for (int qf = 0; qf < 2; ++qf)
      #pragma unroll
      for (int r = 0; r < 4; ++r) redm[wv][qf * 16 + lr * 4 + r] = mx[qf][r];
  }
  __syncthreads();
  #pragma unroll
  for (int qf = 0; qf < 2; ++qf)
    #pragma unroll
    for (int r = 0; r < 4; ++r) {
      float m = redm[0][qf * 16 + lr * 4 + r];
      #pragma unroll
      for (int w2 = 1; w2 < 16; ++w2) m = fmaxf(m, redm[w2][qf * 16 + lr * 4 + r]);
      mx[qf][r] = m;
    }

  #pragma unroll
  for (int qf = 0; qf < 2; ++qf)
    #pragma unroll
    for (int r = 0; r < 4; ++r) {
      float s = 0.f;
      #pragma unroll
      for (int kf = 0; kf < 8; ++kf) {
        const float e = __expf(acc[qf][kf][r] - mx[qf][r]);
        acc[qf][kf][r] = e;
        s += e;
      }
      #pragma unroll
      for (int d = 1; d < 16; d <<= 1) s += __shfl_xor(s, d);
      sm[qf][r] = s;
    }
  if (lc == 0) {
    #pragma unroll
    for (int qf = 0; qf < 2; ++qf)
      #pragma unroll
      for (int r = 0; r < 4; ++r) redl[wv][qf * 16 + lr * 4 + r] = sm[qf][r];
  }
  __syncthreads();
  #pragma unroll
  for (int qf = 0; qf < 2; ++qf)
    #pragma unroll
    for (int r = 0; r < 4; ++r) {
      float s = redl[0][qf * 16 + lr * 4 + r];
      #pragma unroll
      for (int w2 = 1; w2 < 16; ++w2) s += redl[w2][qf * 16 + lr * 4 + r];
      sm[qf][r] = 1.f / s;
    }

  #pragma unroll
  for (int qf = 0; qf < 2; ++qf)
    #pragma unroll
    for (int kf = 0; kf < 8; ++kf) {
      unsigned short o4[4];
      #pragma unroll
      for (int r = 0; r < 4; ++r) o4[r] = f2bf(acc[qf][kf][r] * sm[qf][r]);
      *(uint2*)&bT[((size_t)(b * W_ + kbase + kf * 16 + lc)) * Q_ + q0 + qf * 16 + lr * 4] =
          *(uint2*)o4;
    }
}

// ---------------------------------------------------------------------------
// K3: o1T = beta^T @ h^T, m97-style staged. Tile 128(k) x 128(c), BK=32.
// grid (16, 2, 16), 256 thr, 4 waves 2x2.
// ---------------------------------------------------------------------------
__global__ __launch_bounds__(256)
void k_o1(const unsigned short* __restrict__ bT, const unsigned short* __restrict__ h,
          unsigned short* __restrict__ o1T)
{
  const int b = blockIdx.z, n0 = blockIdx.y * 128, m0 = blockIdx.x * 128;
  const int t = threadIdx.x, l = t & 63, wv = t >> 6;
  const int wr = wv >> 1, wc = wv & 1;

  __shared__ __align__(16) char smraw[34816];   // staging 32KB | epilogue 128x136 bf16
  unsigned short* stg = (unsigned short*)smraw;
  unsigned short (*ot)[136] = (unsigned short(*)[136])smraw;

  const unsigned short* Abase = bT + (size_t)(b * W_ + m0) * Q_;
  const unsigned short* Bbase = h + (size_t)(b * C2 + n0) * Q_;

  const int wub = (t & 192) * 8;
  const int r0s = t >> 2, kcs = (t & 3) * 8;

  auto STAGE = [&](int buf, int q0) {
    #pragma unroll
    for (int i = 0; i < 2; ++i) {
      const int row = i * 64 + r0s;
      gload16(Abase + (size_t)row * Q_ + q0 + kcs, stg + (buf * 2 + 0) * 4096 + i * 2048 + wub);
      gload16(Bbase + (size_t)row * Q_ + q0 + kcs, stg + (buf * 2 + 1) * 4096 + i * 2048 + wub);
    }
  };

  f32x4 acc[4][4];
  #pragma unroll
  for (int i = 0; i < 4; ++i)
    #pragma unroll
    for (int j = 0; j < 4; ++j) acc[i][j] = (f32x4){0.f, 0.f, 0.f, 0.f};

  STAGE(0, 0);
  for (int kt = 0; kt < 32; ++kt) {
    const int cur = kt & 1;
    __syncthreads();
    if (kt + 1 < 32) STAGE(cur ^ 1, (kt + 1) * 32);
    const unsigned short* As = stg + (cur * 2 + 0) * 4096;
    const unsigned short* Bs = stg + (cur * 2 + 1) * 4096;
    bf16x8 a[4], bb[4];
    #pragma unroll
    for (int i = 0; i < 4; ++i)
      a[i] = *(const bf16x8*)&As[(wr * 64 + i * 16 + (l & 15)) * 32 + ((l >> 4) << 3)];
    #pragma unroll
    for (int j = 0; j < 4; ++j)
      bb[j] = *(const bf16x8*)&Bs[(wc * 64 + j * 16 + (l & 15)) * 32 + ((l >> 4) << 3)];
    #pragma unroll
    for (int i = 0; i < 4; ++i)
      #pragma unroll
      for (int j = 0; j < 4; ++j)
        acc[i][j] = MFMA(a[i], bb[j], acc[i][j]);
  }
  __syncthreads();

  const int lr = l >> 4, lc = l & 15;
  #pragma unroll
  for (int i = 0; i < 4; ++i)
    #pragma unroll
    for (int j = 0; j < 4; ++j)
      #pragma unroll
      for (int r = 0; r < 4; ++r)
        ot[wr * 64 + i * 16 + lr * 4 + r][wc * 64 + j * 16 + lc] = f2bf(acc[i][j][r]);
  __syncthreads();
  const int row = t >> 1, half = (t & 1) * 64;
  unsigned short* dst = &o1T[((size_t)(b * W_ + m0 + row)) * C2 + n0 + half];
  #pragma unroll
  for (int u = 0; u < 8; ++u)
    *(uint4*)&dst[u * 8] = *(uint4*)&ot[row][half + u * 8];
}

// ---------------------------------------------------------------------------
// K4: out = gamma*(o1T @ wa^T + ba) + x. (unchanged this round)
// ---------------------------------------------------------------------------
__global__ __launch_bounds__(256)
void k_out(const unsigned short* __restrict__ o1T, const unsigned short* __restrict__ wabf,
           const float* __restrict__ ba, const float* __restrict__ x,
           const float* __restrict__ gamma, float* __restrict__ out)
{
  const int b = blockIdx.z, co0 = blockIdx.y * 128, w0 = blockIdx.x * 128;
  const int t = threadIdx.x, l = t & 63, wv = t >> 6;
  const int wr = wv >> 1, wc = wv & 1;

  const unsigned short* A  = o1T + (size_t)(b * W_ + w0 + wr * 64) * C2;
  const unsigned short* Bt = wabf + (size_t)(co0 + wc * 64) * C2;

  f32x4 acc[4][4];
  #pragma unroll
  for (int i = 0; i < 4; ++i)
    #pragma unroll
    for (int j = 0; j < 4; ++j) acc[i][j] = (f32x4){0.f, 0.f, 0.f, 0.f};

  for (int c0 = 0; c0 < C2; c0 += 32) {
    bf16x8 a[4], bb[4];
    #pragma unroll
    for (int i = 0; i < 4; ++i) a[i]  = ldfrag(A  + (size_t)(i * 16) * C2 + c0, C2);
    #pragma unroll
    for (int j = 0; j < 4; ++j) bb[j] = ldfrag(Bt + (size_t)(j * 16) * C2 + c0, C2);
    #pragma unroll
    for (int i = 0; i < 4; ++i)
      #pragma unroll
      for (int j = 0; j < 4; ++j)
        acc[i][j] = MFMA(a[i], bb[j], acc[i][j]);
  }

  const float gm = gamma[0];
  const int lr = l >> 4, lc = l & 15;
  #pragma unroll
  for (int i = 0; i < 4; ++i)
    #pragma unroll
    for (int j = 0; j < 4; ++j) {
      const int co = co0 + wc * 64 + j * 16 + lc;
      const int w  = w0 + wr * 64 + i * 16 + lr * 4;
      const float bb2 = ba[co];
      const size_t idx = ((size_t)(b * C_ + co)) * W_ + w;
      const float4 xv = *(const float4*)&x[idx];
      float4 ov;
      ov.x = gm * (acc[i][j][0] + bb2) + xv.x;
      ov.y = gm * (acc[i][j][1] + bb2) + xv.y;
      ov.z = gm * (acc[i][j][2] + bb2) + xv.z;
      ov.w = gm * (acc[i][j][3] + bb2) + xv.w;
      *(float4*)&out[idx] = ov;
    }
}

// ---------------------------------------------------------------------------
extern "C" void kernel_launch(void* const* d_in, const int* in_sizes, int n_in,
                              void* d_out, int out_size, void* d_ws, size_t ws_size,
                              hipStream_t stream)
{
  const float* x     = (const float*)d_in[0];
  const float* wf    = (const float*)d_in[1];
  const float* bfp   = (const float*)d_in[2];
  const float* wg    = (const float*)d_in[3];
  const float* bgp   = (const float*)d_in[4];
  const float* wh    = (const float*)d_in[5];
  const float* bhp   = (const float*)d_in[6];
  const float* wa    = (const float*)d_in[7];
  const float* ba    = (const float*)d_in[8];
  const float* gamma = (const float*)d_in[9];
  float* out = (float*)d_out;

  unsigned short* ws = (unsigned short*)d_ws;
  size_t off = 0;
  unsigned short* wbf = ws + off;  off += 393216;
  unsigned short* xT  = ws + off;  off += (size_t)B_ * W_ * C_;
  unsigned short* fT  = ws + off;  off += (size_t)B_ * Q_ * C4;
  unsigned short* gT  = ws + off;  off += (size_t)B_ * W_ * C4;
  unsigned short* h   = ws + off;  off += (size_t)B_ * C2 * Q_;
  unsigned short* bT  = ws + off;  off += (size_t)B_ * W_ * Q_;
  unsigned short* o1T = ws + off;  off += (size_t)B_ * W_ * C2;
  unsigned short* wabf = wbf + 262144;

  k_cvt<<<dim3(1536), dim3(256), 0, stream>>>(wf, wg, wh, wa, wbf);
  k_tx<<<dim3(W_ / 64, C_ / 64, B_), dim3(256), 0, stream>>>(x, xT);
  k_fgh<<<dim3(W_ / 128, 4, B_), dim3(256), 0, stream>>>(xT, wbf, bfp, bgp, bhp, fT, gT, h);
  k_attn<<<dim3(Q_ / 32, B_), dim3(1024), 0, stream>>>(fT, gT, bT);
  k_o1<<<dim3(W_ / 128, 2, B_), dim3(256), 0, stream>>>(bT, h, o1T);
  k_out<<<dim3(W_ / 128, 4, B_), dim3(256), 0, stream>>>(o1T, wabf, ba, x, gamma, out);
}

// Round 7
// 207.702 us; speedup vs baseline: 3.2138x; 1.0165x over previous
//
#include <hip/hip_runtime.h>

#define DI __device__ __forceinline__

constexpr int B_ = 16;
constexpr int C_ = 512;
constexpr int W_ = 2048;
constexpr int C4 = 128;
constexpr int C2 = 256;
constexpr int Q_ = 1024;

typedef short bf16x8 __attribute__((ext_vector_type(8)));
typedef float f32x4 __attribute__((ext_vector_type(4)));

DI f32x4 MFMA(bf16x8 a, bf16x8 b, f32x4 c) {
  return __builtin_amdgcn_mfma_f32_16x16x32_bf16(a, b, c, 0, 0, 0);
}

DI unsigned short f2bf(float v) {
  union { float f; unsigned int i; } c; c.f = v;
  return (unsigned short)((c.i + 0x7FFFu + ((c.i >> 16) & 1u)) >> 16);
}

DI bf16x8 ldfrag(const unsigned short* p, int ld) {
  const int l = threadIdx.x & 63;
  return *(const bf16x8*)(p + (size_t)(l & 15) * ld + ((l >> 4) << 3));
}

// async 16B global->LDS; lds dest is wave-uniform base + lane*16
DI void gload16(const unsigned short* g, unsigned short* l) {
  __builtin_amdgcn_global_load_lds((const __attribute__((address_space(1))) void*)(g),
                                   (__attribute__((address_space(3))) void*)(l), 16, 0, 0);
}

// ---------------------------------------------------------------------------
// Prep 1: weights -> bf16.  [wf 64K][wg 64K][wh 128K][wa 128K]
// ---------------------------------------------------------------------------
__global__ __launch_bounds__(256)
void k_cvt(const float* __restrict__ wf, const float* __restrict__ wg,
           const float* __restrict__ wh, const float* __restrict__ wa,
           unsigned short* __restrict__ dst)
{
  const int i = blockIdx.x * 256 + threadIdx.x;
  float v;
  if (i < 65536)        v = wf[i];
  else if (i < 131072)  v = wg[i - 65536];
  else if (i < 262144)  v = wh[i - 131072];
  else                  v = wa[i - 262144];
  dst[i] = f2bf(v);
}

// ---------------------------------------------------------------------------
// Prep 2: xT[b][w][c] bf16 = transpose of x[b][c][w] f32.
// ---------------------------------------------------------------------------
__global__ __launch_bounds__(256)
void k_tx(const float* __restrict__ x, unsigned short* __restrict__ xT)
{
  __shared__ float tile[64][68];
  const int b = blockIdx.z, c0 = blockIdx.y * 64, w0 = blockIdx.x * 64;
  const int t = threadIdx.x;
  #pragma unroll
  for (int p = 0; p < 4; ++p) {
    const int r = p * 16 + (t >> 4);
    const float4 v = *(const float4*)&x[((size_t)(b * C_ + c0 + r)) * W_ + w0 + (t & 15) * 4];
    *(float4*)&tile[r][(t & 15) * 4] = v;
  }
  __syncthreads();
  const int w = t >> 2, ch = (t & 3) * 16;
  unsigned short o[16];
  #pragma unroll
  for (int j = 0; j < 16; ++j) o[j] = f2bf(tile[ch + j][w]);
  unsigned short* dst = &xT[((size_t)(b * W_ + w0 + w)) * C_ + c0 + ch];
  *(uint4*)&dst[0] = *(uint4*)&o[0];
  *(uint4*)&dst[8] = *(uint4*)&o[8];
}

// ---------------------------------------------------------------------------
// K1: m97-style LDS-staged GEMM. Tile 128(w) x 128(ch), BK=32, 4 waves 2x2.
// rt=0 -> fT (pooled,T), rt=1 -> gT (T), rt=2,3 -> h (pooled). grid (16,4,16)
// ---------------------------------------------------------------------------
__global__ __launch_bounds__(256)
void k_fgh(const unsigned short* __restrict__ xT, const unsigned short* __restrict__ wcat,
           const float* __restrict__ bfp, const float* __restrict__ bgp,
           const float* __restrict__ bhp,
           unsigned short* __restrict__ fT, unsigned short* __restrict__ gT,
           unsigned short* __restrict__ h)
{
  const int b = blockIdx.z, rt = blockIdx.y, w0 = blockIdx.x * 128;
  const int t = threadIdx.x, l = t & 63, wv = t >> 6;
  const int wr = wv >> 1, wc = wv & 1;

  __shared__ __align__(16) char smraw[33792];   // staging 32KB | epilogue 64x132 f32
  unsigned short* stg = (unsigned short*)smraw; // [buf][ab][4096]
  float (*eps)[132] = (float(*)[132])smraw;

  const unsigned short* Abase = xT + ((size_t)(b * W_ + w0)) * C_;
  const unsigned short* Bbase = wcat + (size_t)(rt * 128) * C_;

  const int wub = (t & 192) * 8;          // wave-uniform lds elem base per instr block
  const int r0s = t >> 2, kcs = (t & 3) * 8;

  auto STAGE = [&](int buf, int c0) {
    #pragma unroll
    for (int i = 0; i < 2; ++i) {
      const int row = i * 64 + r0s;
      gload16(Abase + (size_t)row * C_ + c0 + kcs, stg + (buf * 2 + 0) * 4096 + i * 2048 + wub);
      gload16(Bbase + (size_t)row * C_ + c0 + kcs, stg + (buf * 2 + 1) * 4096 + i * 2048 + wub);
    }
  };

  f32x4 acc[4][4];
  #pragma unroll
  for (int i = 0; i < 4; ++i)
    #pragma unroll
    for (int j = 0; j < 4; ++j) acc[i][j] = (f32x4){0.f, 0.f, 0.f, 0.f};

  STAGE(0, 0);
  for (int kt = 0; kt < 16; ++kt) {
    const int cur = kt & 1;
    __syncthreads();                       // drains vmcnt -> buf[cur] ready
    if (kt + 1 < 16) STAGE(cur ^ 1, (kt + 1) * 32);
    const unsigned short* As = stg + (cur * 2 + 0) * 4096;
    const unsigned short* Bs = stg + (cur * 2 + 1) * 4096;
    bf16x8 a[4], bb[4];
    #pragma unroll
    for (int i = 0; i < 4; ++i)
      a[i] = *(const bf16x8*)&As[(wr * 64 + i * 16 + (l & 15)) * 32 + ((l >> 4) << 3)];
    #pragma unroll
    for (int j = 0; j < 4; ++j)
      bb[j] = *(const bf16x8*)&Bs[(wc * 64 + j * 16 + (l & 15)) * 32 + ((l >> 4) << 3)];
    #pragma unroll
    for (int i = 0; i < 4; ++i)
      #pragma unroll
      for (int j = 0; j < 4; ++j)
        acc[i][j] = MFMA(a[i], bb[j], acc[i][j]);
  }
  __syncthreads();                          // staging arena -> epilogue overlay

  const int lr = l >> 4, lc = l & 15;

  if (rt == 1) {
    #pragma unroll
    for (int p = 0; p < 2; ++p) {
      if (p) __syncthreads();
      if (wr == p) {
        #pragma unroll
        for (int i = 0; i < 4; ++i)
          #pragma unroll
          for (int j = 0; j < 4; ++j)
            #pragma unroll
            for (int r = 0; r < 4; ++r)
              eps[i * 16 + lr * 4 + r][wc * 64 + j * 16 + lc] = acc[i][j][r];
      }
      __syncthreads();
      const int row = t >> 2, chunk = (t & 3) * 32;
      unsigned short o[32];
      #pragma unroll
      for (int j2 = 0; j2 < 32; ++j2) o[j2] = f2bf(eps[row][chunk + j2] + bgp[chunk + j2]);
      unsigned short* dst = &gT[((size_t)(b * W_ + w0 + p * 64 + row)) * C4 + chunk];
      #pragma unroll
      for (int u = 0; u < 4; ++u) *(uint4*)&dst[u * 8] = *(uint4*)&o[u * 8];
    }
  } else {
    #pragma unroll
    for (int i = 0; i < 4; ++i)
      #pragma unroll
      for (int j = 0; j < 4; ++j)
        #pragma unroll
        for (int jj = 0; jj < 2; ++jj)
          eps[wr * 32 + i * 8 + lr * 2 + jj][wc * 64 + j * 16 + lc] =
              fmaxf(acc[i][j][2 * jj], acc[i][j][2 * jj + 1]);
    __syncthreads();
    if (rt == 0) {
      const int row = t >> 2, chunk = (t & 3) * 32;
      unsigned short o[32];
      #pragma unroll
      for (int j2 = 0; j2 < 32; ++j2) o[j2] = f2bf(eps[row][chunk + j2] + bfp[chunk + j2]);
      unsigned short* dst = &fT[((size_t)(b * Q_ + (w0 >> 1) + row)) * C4 + chunk];
      #pragma unroll
      for (int u = 0; u < 4; ++u) *(uint4*)&dst[u * 8] = *(uint4*)&o[u * 8];
    } else {
      const int ch = t >> 1, half = (t & 1) * 32;
      const float bv = bhp[(rt - 2) * 128 + ch];
      unsigned short o[32];
      #pragma unroll
      for (int qq = 0; qq < 32; ++qq) o[qq] = f2bf(eps[half + qq][ch] + bv);
      unsigned short* dst = &h[((size_t)(b * C2 + (rt - 2) * 128 + ch)) * Q_ + (w0 >> 1) + half];
      #pragma unroll
      for (int u = 0; u < 4; ++u) *(uint4*)&dst[u * 8] = *(uint4*)&o[u * 8];
    }
  }
}

// ---------------------------------------------------------------------------
// K2 v4: s = fT @ gT^T with LDS-staged, block-shared B panel.
// Block: 32 q x 2048 k, 16 waves; 16 n-chunks of 128 k, dbuf global_load_lds.
// Wave (qf=wv>>3, kf=wv&7) computes one 16x16 tile/chunk; s in regs (sacc[16]).
// B LDS XOR-swizzled (granule ^= row&15): linear dest + inv-swz SRC + swz READ.
// grid (Q/32, B), 1024 thr
// ---------------------------------------------------------------------------
__global__ __launch_bounds__(1024)
void k_attn(const unsigned short* __restrict__ fT, const unsigned short* __restrict__ gT,
            unsigned short* __restrict__ bT)
{
  const int b = blockIdx.y, q0 = blockIdx.x * 32;
  const int t = threadIdx.x, l = t & 63, wv = t >> 6;   // 16 waves
  const int qf = wv >> 3, kf = wv & 7;
  const int lcq = l & 15, lrq = l >> 4;

  __shared__ __align__(16) unsigned short Alds[32 * 128];       //  8 KB
  __shared__ __align__(16) unsigned short Blds[2][128 * 128];   // 64 KB
  __shared__ float redm[16][16];
  __shared__ float redl[16][16];

  // stage A once (linear): waves 0..7, rows 4w..4w+3
  if (wv < 8) {
    gload16(fT + ((size_t)(b * Q_ + q0 + wv * 4 + lrq)) * C4 + lcq * 8,
            Alds + wv * 512);
  }

  const unsigned short* Bbase = gT + (size_t)(b * W_) * C4;
  // stage B chunk nc into buf: dest linear; src col-granule pre-swizzled by row&15
  auto STAGEB = [&](int buf, int nc) {
    #pragma unroll
    for (int i = 0; i < 2; ++i) {
      const int row = i * 64 + wv * 4 + lrq;          // 0..127
      const int cg  = lcq ^ (row & 15);               // inverse swizzle on source
      gload16(Bbase + ((size_t)(nc * 128 + row)) * C4 + cg * 8,
              Blds[buf] + i * 8192 + wv * 512);
    }
  };

  STAGEB(0, 0);
  __syncthreads();     // drains A + B0

  // hoist A fragments (4 reads total; conflicts negligible)
  bf16x8 aT[4];
  #pragma unroll
  for (int kk = 0; kk < 4; ++kk)
    aT[kk] = *(const bf16x8*)&Alds[(qf * 16 + lcq) * 128 + kk * 32 + lrq * 8];

  f32x4 sacc[16];
  #pragma unroll
  for (int nc = 0; nc < 16; ++nc) sacc[nc] = (f32x4){0.f, 0.f, 0.f, 0.f};

  #pragma unroll
  for (int nc = 0; nc < 16; ++nc) {
    const int cur = nc & 1;
    if (nc) __syncthreads();              // drains stage of buf[cur]
    if (nc + 1 < 16) STAGEB(cur ^ 1, nc + 1);
    #pragma unroll
    for (int kk = 0; kk < 4; ++kk) {
      // read row kf*16+lcq, data granule kk*4+lrq, swizzled by row&15 (= lcq)
      const bf16x8 bb = *(const bf16x8*)
          &Blds[cur][(kf * 16 + lcq) * 128 + ((kk * 4 + lrq) ^ lcq) * 8];
      sacc[nc] = MFMA(aT[kk], bb, sacc[nc]);
    }
  }

  // ---- softmax over k (per lane: 4 q's via reg r, 16 k's via nc) ----
  float mx[4], inv[4];
  #pragma unroll
  for (int r = 0; r < 4; ++r) {
    float m = sacc[0][r];
    #pragma unroll
    for (int nc = 1; nc < 16; ++nc) m = fmaxf(m, sacc[nc][r]);
    #pragma unroll
    for (int d = 1; d < 16; d <<= 1) m = fmaxf(m, __shfl_xor(m, d));
    mx[r] = m;
  }
  if (lcq == 0) {
    #pragma unroll
    for (int r = 0; r < 4; ++r) redm[wv][lrq * 4 + r] = mx[r];
  }
  __syncthreads();
  #pragma unroll
  for (int r = 0; r < 4; ++r) {
    float m = redm[qf * 8][lrq * 4 + r];
    #pragma unroll
    for (int w2 = 1; w2 < 8; ++w2) m = fmaxf(m, redm[qf * 8 + w2][lrq * 4 + r]);
    mx[r] = m;
  }
  #pragma unroll
  for (int r = 0; r < 4; ++r) {
    float s = 0.f;
    #pragma unroll
    for (int nc = 0; nc < 16; ++nc) {
      const float e = __expf(sacc[nc][r] - mx[r]);
      sacc[nc][r] = e;
      s += e;
    }
    #pragma unroll
    for (int d = 1; d < 16; d <<= 1) s += __shfl_xor(s, d);
    inv[r] = s;
  }
  if (lcq == 0) {
    #pragma unroll
    for (int r = 0; r < 4; ++r) redl[wv][lrq * 4 + r] = inv[r];
  }
  __syncthreads();
  #pragma unroll
  for (int r = 0; r < 4; ++r) {
    float s = redl[qf * 8][lrq * 4 + r];
    #pragma unroll
    for (int w2 = 1; w2 < 8; ++w2) s += redl[qf * 8 + w2][lrq * 4 + r];
    inv[r] = 1.f / s;
  }

  // write beta^T[k][q]: per lane one k (kf*16+lcq per chunk), 4 q's (uint2)
  #pragma unroll
  for (int nc = 0; nc < 16; ++nc) {
    unsigned short o4[4];
    #pragma unroll
    for (int r = 0; r < 4; ++r) o4[r] = f2bf(sacc[nc][r] * inv[r]);
    *(uint2*)&bT[((size_t)(b * W_ + nc * 128 + kf * 16 + lcq)) * Q_ + q0 + qf * 16 + lrq * 4] =
        *(uint2*)o4;
  }
}

// ---------------------------------------------------------------------------
// K3: o1T = beta^T @ h^T, m97-style staged. Tile 128(k) x 128(c), BK=32.
// grid (16, 2, 16), 256 thr, 4 waves 2x2.
// ---------------------------------------------------------------------------
__global__ __launch_bounds__(256)
void k_o1(const unsigned short* __restrict__ bT, const unsigned short* __restrict__ h,
          unsigned short* __restrict__ o1T)
{
  const int b = blockIdx.z, n0 = blockIdx.y * 128, m0 = blockIdx.x * 128;
  const int t = threadIdx.x, l = t & 63, wv = t >> 6;
  const int wr = wv >> 1, wc = wv & 1;

  __shared__ __align__(16) char smraw[34816];   // staging 32KB | epilogue 128x136 bf16
  unsigned short* stg = (unsigned short*)smraw;
  unsigned short (*ot)[136] = (unsigned short(*)[136])smraw;

  const unsigned short* Abase = bT + (size_t)(b * W_ + m0) * Q_;
  const unsigned short* Bbase = h + (size_t)(b * C2 + n0) * Q_;

  const int wub = (t & 192) * 8;
  const int r0s = t >> 2, kcs = (t & 3) * 8;

  auto STAGE = [&](int buf, int q0) {
    #pragma unroll
    for (int i = 0; i < 2; ++i) {
      const int row = i * 64 + r0s;
      gload16(Abase + (size_t)row * Q_ + q0 + kcs, stg + (buf * 2 + 0) * 4096 + i * 2048 + wub);
      gload16(Bbase + (size_t)row * Q_ + q0 + kcs, stg + (buf * 2 + 1) * 4096 + i * 2048 + wub);
    }
  };

  f32x4 acc[4][4];
  #pragma unroll
  for (int i = 0; i < 4; ++i)
    #pragma unroll
    for (int j = 0; j < 4; ++j) acc[i][j] = (f32x4){0.f, 0.f, 0.f, 0.f};

  STAGE(0, 0);
  for (int kt = 0; kt < 32; ++kt) {
    const int cur = kt & 1;
    __syncthreads();
    if (kt + 1 < 32) STAGE(cur ^ 1, (kt + 1) * 32);
    const unsigned short* As = stg + (cur * 2 + 0) * 4096;
    const unsigned short* Bs = stg + (cur * 2 + 1) * 4096;
    bf16x8 a[4], bb[4];
    #pragma unroll
    for (int i = 0; i < 4; ++i)
      a[i] = *(const bf16x8*)&As[(wr * 64 + i * 16 + (l & 15)) * 32 + ((l >> 4) << 3)];
    #pragma unroll
    for (int j = 0; j < 4; ++j)
      bb[j] = *(const bf16x8*)&Bs[(wc * 64 + j * 16 + (l & 15)) * 32 + ((l >> 4) << 3)];
    #pragma unroll
    for (int i = 0; i < 4; ++i)
      #pragma unroll
      for (int j = 0; j < 4; ++j)
        acc[i][j] = MFMA(a[i], bb[j], acc[i][j]);
  }
  __syncthreads();

  const int lr = l >> 4, lc = l & 15;
  #pragma unroll
  for (int i = 0; i < 4; ++i)
    #pragma unroll
    for (int j = 0; j < 4; ++j)
      #pragma unroll
      for (int r = 0; r < 4; ++r)
        ot[wr * 64 + i * 16 + lr * 4 + r][wc * 64 + j * 16 + lc] = f2bf(acc[i][j][r]);
  __syncthreads();
  const int row = t >> 1, half = (t & 1) * 64;
  unsigned short* dst = &o1T[((size_t)(b * W_ + m0 + row)) * C2 + n0 + half];
  #pragma unroll
  for (int u = 0; u < 8; ++u)
    *(uint4*)&dst[u * 8] = *(uint4*)&ot[row][half + u * 8];
}

// ---------------------------------------------------------------------------
// K4: out = gamma*(o1T @ wa^T + ba) + x. (unchanged this round)
// ---------------------------------------------------------------------------
__global__ __launch_bounds__(256)
void k_out(const unsigned short* __restrict__ o1T, const unsigned short* __restrict__ wabf,
           const float* __restrict__ ba, const float* __restrict__ x,
           const float* __restrict__ gamma, float* __restrict__ out)
{
  const int b = blockIdx.z, co0 = blockIdx.y * 128, w0 = blockIdx.x * 128;
  const int t = threadIdx.x, l = t & 63, wv = t >> 6;
  const int wr = wv >> 1, wc = wv & 1;

  const unsigned short* A  = o1T + (size_t)(b * W_ + w0 + wr * 64) * C2;
  const unsigned short* Bt = wabf + (size_t)(co0 + wc * 64) * C2;

  f32x4 acc[4][4];
  #pragma unroll
  for (int i = 0; i < 4; ++i)
    #pragma unroll
    for (int j = 0; j < 4; ++j) acc[i][j] = (f32x4){0.f, 0.f, 0.f, 0.f};

  for (int c0 = 0; c0 < C2; c0 += 32) {
    bf16x8 a[4], bb[4];
    #pragma unroll
    for (int i = 0; i < 4; ++i) a[i]  = ldfrag(A  + (size_t)(i * 16) * C2 + c0, C2);
    #pragma unroll
    for (int j = 0; j < 4; ++j) bb[j] = ldfrag(Bt + (size_t)(j * 16) * C2 + c0, C2);
    #pragma unroll
    for (int i = 0; i < 4; ++i)
      #pragma unroll
      for (int j = 0; j < 4; ++j)
        acc[i][j] = MFMA(a[i], bb[j], acc[i][j]);
  }

  const float gm = gamma[0];
  const int lr = l >> 4, lc = l & 15;
  #pragma unroll
  for (int i = 0; i < 4; ++i)
    #pragma unroll
    for (int j = 0; j < 4; ++j) {
      const int co = co0 + wc * 64 + j * 16 + lc;
      const int w  = w0 + wr * 64 + i * 16 + lr * 4;
      const float bb2 = ba[co];
      const size_t idx = ((size_t)(b * C_ + co)) * W_ + w;
      const float4 xv = *(const float4*)&x[idx];
      float4 ov;
      ov.x = gm * (acc[i][j][0] + bb2) + xv.x;
      ov.y = gm * (acc[i][j][1] + bb2) + xv.y;
      ov.z = gm * (acc[i][j][2] + bb2) + xv.z;
      ov.w = gm * (acc[i][j][3] + bb2) + xv.w;
      *(float4*)&out[idx] = ov;
    }
}

// ---------------------------------------------------------------------------
extern "C" void kernel_launch(void* const* d_in, const int* in_sizes, int n_in,
                              void* d_out, int out_size, void* d_ws, size_t ws_size,
                              hipStream_t stream)
{
  const float* x     = (const float*)d_in[0];
  const float* wf    = (const float*)d_in[1];
  const float* bfp   = (const float*)d_in[2];
  const float* wg    = (const float*)d_in[3];
  const float* bgp   = (const float*)d_in[4];
  const float* wh    = (const float*)d_in[5];
  const float* bhp   = (const float*)d_in[6];
  const float* wa    = (const float*)d_in[7];
  const float* ba    = (const float*)d_in[8];
  const float* gamma = (const float*)d_in[9];
  float* out = (float*)d_out;

  unsigned short* ws = (unsigned short*)d_ws;
  size_t off = 0;
  unsigned short* wbf = ws + off;  off += 393216;
  unsigned short* xT  = ws + off;  off += (size_t)B_ * W_ * C_;
  unsigned short* fT  = ws + off;  off += (size_t)B_ * Q_ * C4;
  unsigned short* gT  = ws + off;  off += (size_t)B_ * W_ * C4;
  unsigned short* h   = ws + off;  off += (size_t)B_ * C2 * Q_;
  unsigned short* bT  = ws + off;  off += (size_t)B_ * W_ * Q_;
  unsigned short* o1T = ws + off;  off += (size_t)B_ * W_ * C2;
  unsigned short* wabf = wbf + 262144;

  k_cvt<<<dim3(1536), dim3(256), 0, stream>>>(wf, wg, wh, wa, wbf);
  k_tx<<<dim3(W_ / 64, C_ / 64, B_), dim3(256), 0, stream>>>(x, xT);
  k_fgh<<<dim3(W_ / 128, 4, B_), dim3(256), 0, stream>>>(xT, wbf, bfp, bgp, bhp, fT, gT, h);
  k_attn<<<dim3(Q_ / 32, B_), dim3(1024), 0, stream>>>(fT, gT, bT);
  k_o1<<<dim3(W_ / 128, 2, B_), dim3(256), 0, stream>>>(bT, h, o1T);
  k_out<<<dim3(W_ / 128, 4, B_), dim3(256), 0, stream>>>(o1T, wabf, ba, x, gamma, out);
}